// Round 6
// baseline (340.383 us; speedup 1.0000x reference)
//
#include <hip/hip_runtime.h>
#include <math.h>

#define EMB 1024
#define HEADS 16
#define HD 64
#define FF_DIM 4096
#define SEQ 2048
#define BATCH 2
#define NTOK (BATCH * SEQ)   // 4096

typedef __bf16 bf16x8 __attribute__((ext_vector_type(8)));
typedef float f32x4 __attribute__((ext_vector_type(4)));

__device__ __forceinline__ unsigned short f2bf(float f) {
    union { float f; unsigned int u; } v; v.f = f;
    unsigned int r = v.u + 0x7fff + ((v.u >> 16) & 1);  // RNE
    return (unsigned short)(r >> 16);
}

// pack 2 fp32 -> 2 bf16 in one u32 (no builtin on gfx950; inline asm)
__device__ __forceinline__ unsigned int cvt_pk_bf16(float a, float b) {
    unsigned int r;
    asm("v_cvt_pk_bf16_f32 %0, %1, %2" : "=v"(r) : "v"(a), "v"(b));
    return r;
}

// gelu_tanh(x) = 0.5x(1+tanh(z)) = x*sigmoid(2z), z = c(x+0.044715x^3).
__device__ __forceinline__ float gelu_f(float x) {
    const float A = 1.5957691216057308f;   // 2c, c = sqrt(2/pi)
    const float B = 0.07135481282989427f;  // 2c*0.044715
    float zz = x * (A + B * x * x);
    return x * __builtin_amdgcn_rcpf(1.f + __expf(-zz));
}

#define GLOAD_LDS16(g, l)                                                      \
    __builtin_amdgcn_global_load_lds(                                          \
        (const __attribute__((address_space(1))) void*)(g),                    \
        (__attribute__((address_space(3))) void*)(l), 16, 0, 0)

// ---------------------------------------------------------------------------
// LayerNorm: one block per row of 1024, fp32 in -> bf16 out.
// float4 loads (16B/lane), ushort4 packed stores (G13).
// ---------------------------------------------------------------------------
__global__ __launch_bounds__(256) void ln_kernel(const float* __restrict__ x,
                                                 const float* __restrict__ scale,
                                                 const float* __restrict__ shift,
                                                 unsigned short* __restrict__ out) {
    int row = blockIdx.x;
    const float4* xr = (const float4*)(x + (size_t)row * EMB);
    int t = threadIdx.x;

    float4 v = xr[t];
    float s = v.x + v.y + v.z + v.w;
    float s2 = v.x * v.x + v.y * v.y + v.z * v.z + v.w * v.w;
    for (int o = 32; o > 0; o >>= 1) {
        s += __shfl_down(s, o, 64);
        s2 += __shfl_down(s2, o, 64);
    }
    __shared__ float red[4], red2[4];
    int wave = t >> 6;
    if ((t & 63) == 0) { red[wave] = s; red2[wave] = s2; }
    __syncthreads();
    if (t == 0) {
        float a = 0.f, b = 0.f;
#pragma unroll
        for (int i = 0; i < 4; i++) { a += red[i]; b += red2[i]; }
        red[0] = a; red2[0] = b;
    }
    __syncthreads();
    float mean = red[0] * (1.f / EMB);
    float var = red2[0] * (1.f / EMB) - mean * mean;
    float rstd = rsqrtf(var + 1e-5f);

    float4 sc = ((const float4*)scale)[t];
    float4 sh = ((const float4*)shift)[t];
    ushort4 o;
    o.x = f2bf(sc.x * (v.x - mean) * rstd + sh.x);
    o.y = f2bf(sc.y * (v.y - mean) * rstd + sh.y);
    o.z = f2bf(sc.z * (v.z - mean) * rstd + sh.z);
    o.w = f2bf(sc.w * (v.w - mean) * rstd + sh.w);
    ((ushort4*)(out + (size_t)row * EMB))[t] = o;
}

// ---------------------------------------------------------------------------
// Fused prep: blocks [0,3072) = weight transpose+cast (6 weights),
//             blocks [3072,7168) = LN1 row (x -> lnO bf16, float4 path).
// ---------------------------------------------------------------------------
__global__ __launch_bounds__(256) void prep_kernel(
    const float* __restrict__ w0, const float* __restrict__ w1,
    const float* __restrict__ w2, const float* __restrict__ w3,
    const float* __restrict__ w4, const float* __restrict__ w5,
    unsigned short* __restrict__ o0, unsigned short* __restrict__ o1,
    unsigned short* __restrict__ o2, unsigned short* __restrict__ o3,
    unsigned short* __restrict__ o4, unsigned short* __restrict__ o5,
    const float* __restrict__ x, const float* __restrict__ ln1s,
    const float* __restrict__ ln1b, unsigned short* __restrict__ lnO) {
    __shared__ float tile[64][65];
    __shared__ float red[4], red2[4];
    int id = blockIdx.x;
    int t = threadIdx.x;

    if (id >= 3072) {
        // ---- LN1 path ----
        int row = id - 3072;
        const float4* xr = (const float4*)(x + (size_t)row * EMB);
        float4 v = xr[t];
        float s = v.x + v.y + v.z + v.w;
        float s2 = v.x * v.x + v.y * v.y + v.z * v.z + v.w * v.w;
        for (int o = 32; o > 0; o >>= 1) {
            s += __shfl_down(s, o, 64);
            s2 += __shfl_down(s2, o, 64);
        }
        int wave = t >> 6;
        if ((t & 63) == 0) { red[wave] = s; red2[wave] = s2; }
        __syncthreads();
        if (t == 0) {
            float a = 0.f, b = 0.f;
#pragma unroll
            for (int i = 0; i < 4; i++) { a += red[i]; b += red2[i]; }
            red[0] = a; red2[0] = b;
        }
        __syncthreads();
        float mean = red[0] * (1.f / EMB);
        float var = red2[0] * (1.f / EMB) - mean * mean;
        float rstd = rsqrtf(var + 1e-5f);

        float4 sc = ((const float4*)ln1s)[t];
        float4 sh = ((const float4*)ln1b)[t];
        ushort4 o;
        o.x = f2bf(sc.x * (v.x - mean) * rstd + sh.x);
        o.y = f2bf(sc.y * (v.y - mean) * rstd + sh.y);
        o.z = f2bf(sc.z * (v.z - mean) * rstd + sh.z);
        o.w = f2bf(sc.w * (v.w - mean) * rstd + sh.w);
        ((ushort4*)(lnO + (size_t)row * EMB))[t] = o;
        return;
    }

    // ---- transpose+cast path ----
    const float* src; unsigned short* dst; int K, N, lid;
    if (id < 256)       { src = w0; dst = o0; K = 1024; N = 1024; lid = id; }
    else if (id < 512)  { src = w1; dst = o1; K = 1024; N = 1024; lid = id - 256; }
    else if (id < 768)  { src = w2; dst = o2; K = 1024; N = 1024; lid = id - 512; }
    else if (id < 1024) { src = w3; dst = o3; K = 1024; N = 1024; lid = id - 768; }
    else if (id < 2048) { src = w4; dst = o4; K = 1024; N = 4096; lid = id - 1024; }
    else                { src = w5; dst = o5; K = 4096; N = 1024; lid = id - 2048; }
    int tn = N >> 6;
    int k0 = (lid / tn) << 6, n0 = (lid % tn) << 6;
    int rr = t >> 6, cc = t & 63;
#pragma unroll
    for (int i = 0; i < 16; i++) {
        int r = i * 4 + rr;
        tile[r][cc] = src[(size_t)(k0 + r) * N + n0 + cc];
    }
    __syncthreads();
#pragma unroll
    for (int i = 0; i < 16; i++) {
        int r = i * 4 + rr;
        dst[(size_t)(n0 + r) * K + k0 + cc] = f2bf(tile[cc][r]);
    }
}

// ===========================================================================
// BK=64 staging geometry: LDS row = 64 elems (128 B) = 8 x 16B chunks.
// Physical chunk p of row r holds logical chunk p ^ (r & 7); fragment
// ds_read_b128 aliases 2-way (free). Per global_load_lds instr: 8 rows;
// lane l -> row base+(l>>3), logical chunk (l&7)^(l>>3).
// ===========================================================================

// ---------------------------------------------------------------------------
// FF1 GEMM, 128x128 tile, BK=64 double-buffered (r0-proven).
// Epilogue: bf16 gelu(acc + bias[n]).
// ---------------------------------------------------------------------------
__global__ __launch_bounds__(256) void ff1_gemm(
    const unsigned short* __restrict__ A,   // M x K bf16
    const unsigned short* __restrict__ Bt,  // N x K bf16
    unsigned short* __restrict__ C,
    const float* __restrict__ bias,
    int M, int N, int K) {
    __shared__ unsigned short As[2][128 * 64];  // 32 KB
    __shared__ unsigned short Bs[2][128 * 64];  // 32 KB

    const int t = threadIdx.x;
    const int w = t >> 6, lane = t & 63;
    const int m0 = blockIdx.x * 128, n0 = blockIdx.y * 128;

    const int srow = lane >> 3;
    const int sc = (lane & 7) ^ srow;   // logical chunk (elems*8)
    const unsigned short* gA[4];
    const unsigned short* gB[4];
#pragma unroll
    for (int i = 0; i < 4; i++) {
        gA[i] = A + (size_t)(m0 + i * 32 + w * 8 + srow) * K + sc * 8;
        gB[i] = Bt + (size_t)(n0 + i * 32 + w * 8 + srow) * K + sc * 8;
    }

    const int mrow = (w >> 1) * 64, ncol = (w & 1) * 64;
    int ph[2];
#pragma unroll
    for (int s = 0; s < 2; s++) ph[s] = ((s * 4 + (lane >> 4)) ^ (lane & 7)) * 8;
    int abase[4], bbase[4];
#pragma unroll
    for (int i = 0; i < 4; i++) {
        abase[i] = (mrow + i * 16 + (lane & 15)) * 64;
        bbase[i] = (ncol + i * 16 + (lane & 15)) * 64;
    }

    f32x4 acc[4][4];
#pragma unroll
    for (int i = 0; i < 4; i++)
#pragma unroll
        for (int j = 0; j < 4; j++) acc[i][j] = (f32x4){0.f, 0.f, 0.f, 0.f};

#define STG1(b)                                                                \
    do {                                                                       \
        _Pragma("unroll") for (int i_ = 0; i_ < 4; i_++) {                     \
            GLOAD_LDS16(gA[i_], &As[b][(i_ * 32 + w * 8) * 64]);               \
            GLOAD_LDS16(gB[i_], &Bs[b][(i_ * 32 + w * 8) * 64]);               \
            gA[i_] += 64; gB[i_] += 64;                                        \
        }                                                                      \
    } while (0)

    STG1(0);
    const int nk = K >> 6;
    for (int it = 0; it < nk; it++) {
        const int buf = it & 1;
        __syncthreads();
        if (it + 1 < nk) STG1(buf ^ 1);
#pragma unroll
        for (int s = 0; s < 2; s++) {
            bf16x8 af[4], bfr[4];
#pragma unroll
            for (int i = 0; i < 4; i++) {
                af[i] = *reinterpret_cast<const bf16x8*>(&As[buf][abase[i] + ph[s]]);
                bfr[i] = *reinterpret_cast<const bf16x8*>(&Bs[buf][bbase[i] + ph[s]]);
            }
#pragma unroll
            for (int i = 0; i < 4; i++)
#pragma unroll
                for (int j = 0; j < 4; j++)
                    acc[i][j] = __builtin_amdgcn_mfma_f32_16x16x32_bf16(
                        af[i], bfr[j], acc[i][j], 0, 0, 0);
        }
    }
#undef STG1

    const int ccol = lane & 15;
    const int crow = (lane >> 4) << 2;
#pragma unroll
    for (int i = 0; i < 4; i++) {
#pragma unroll
        for (int j = 0; j < 4; j++) {
            int col = n0 + ncol + j * 16 + ccol;
            float badd = bias[col];
#pragma unroll
            for (int r = 0; r < 4; r++) {
                int row = m0 + mrow + i * 16 + crow + r;
                C[(size_t)row * N + col] = f2bf(gelu_f(acc[i][j][r] + badd));
            }
        }
    }
}

// ---------------------------------------------------------------------------
// N=1024 GEMM, 64x64 tile, BK=64 double-buffered, XCD mapping (x = m-tile).
// Grid (M/64, N/64) = 64x16 = 1024 blocks.  (O-proj only now.)
// EPI 1: C = acc + bias[n] + resid (fp32); v6: resid PREFETCHED before the
// K-loop (16 VGPR) so the 16 MB read hides under compute, not the tail.
// ---------------------------------------------------------------------------
template <int EPI>
__global__ __launch_bounds__(256) void mfma_gemm_s64(
    const unsigned short* __restrict__ A,   // M x K bf16
    const unsigned short* __restrict__ Bt,  // N x K bf16
    float* __restrict__ C,
    const float* __restrict__ bias,
    const float* __restrict__ resid,
    int M, int N, int K) {
    __shared__ unsigned short As[2][64 * 64];  // 16 KB
    __shared__ unsigned short Bs[2][64 * 64];  // 16 KB

    const int t = threadIdx.x;
    const int w = t >> 6, lane = t & 63;
    const int m0 = blockIdx.x * 64, n0 = blockIdx.y * 64;

    const int srow = lane >> 3;
    const int sc = (lane & 7) ^ srow;
    const unsigned short* gA[2];
    const unsigned short* gB[2];
#pragma unroll
    for (int i = 0; i < 2; i++) {
        gA[i] = A + (size_t)(m0 + i * 32 + w * 8 + srow) * K + sc * 8;
        gB[i] = Bt + (size_t)(n0 + i * 32 + w * 8 + srow) * K + sc * 8;
    }

    int ph[2];
#pragma unroll
    for (int s = 0; s < 2; s++) ph[s] = ((s * 4 + (lane >> 4)) ^ (lane & 7)) * 8;
    // wave tile 32x32: rows mrow..mrow+31, cols ncol..ncol+31
    const int mrow = (w >> 1) * 32, ncol = (w & 1) * 32;
    int abase[2], bbase[2];
#pragma unroll
    for (int i = 0; i < 2; i++) {
        abase[i] = (mrow + i * 16 + (lane & 15)) * 64;
        bbase[i] = (ncol + i * 16 + (lane & 15)) * 64;
    }

    const int ccol = lane & 15;
    const int crow = (lane >> 4) << 2;

    // prefetch resid tile into registers (EPI 1 only): hides the HBM read
    float rpre[2][2][4];
    if constexpr (EPI == 1) {
#pragma unroll
        for (int i = 0; i < 2; i++)
#pragma unroll
            for (int j = 0; j < 2; j++)
#pragma unroll
                for (int r = 0; r < 4; r++) {
                    int row = m0 + mrow + i * 16 + crow + r;
                    int col = n0 + ncol + j * 16 + ccol;
                    rpre[i][j][r] = resid[(size_t)row * N + col];
                }
    }

    f32x4 acc[2][2];
#pragma unroll
    for (int i = 0; i < 2; i++)
#pragma unroll
        for (int j = 0; j < 2; j++) acc[i][j] = (f32x4){0.f, 0.f, 0.f, 0.f};

#define STGS(b)                                                                \
    do {                                                                       \
        _Pragma("unroll") for (int i_ = 0; i_ < 2; i_++) {                     \
            GLOAD_LDS16(gA[i_], &As[b][(i_ * 32 + w * 8) * 64]);               \
            GLOAD_LDS16(gB[i_], &Bs[b][(i_ * 32 + w * 8) * 64]);               \
            gA[i_] += 64; gB[i_] += 64;                                        \
        }                                                                      \
    } while (0)

    STGS(0);
    const int nk = K >> 6;
    for (int it = 0; it < nk; it++) {
        const int buf = it & 1;
        __syncthreads();
        if (it + 1 < nk) STGS(buf ^ 1);
#pragma unroll
        for (int s = 0; s < 2; s++) {
            bf16x8 af[2], bfr[2];
#pragma unroll
            for (int i = 0; i < 2; i++) {
                af[i] = *reinterpret_cast<const bf16x8*>(&As[buf][abase[i] + ph[s]]);
                bfr[i] = *reinterpret_cast<const bf16x8*>(&Bs[buf][bbase[i] + ph[s]]);
            }
#pragma unroll
            for (int i = 0; i < 2; i++)
#pragma unroll
                for (int j = 0; j < 2; j++)
                    acc[i][j] = __builtin_amdgcn_mfma_f32_16x16x32_bf16(
                        af[i], bfr[j], acc[i][j], 0, 0, 0);
        }
    }
#undef STGS

#pragma unroll
    for (int i = 0; i < 2; i++) {
#pragma unroll
        for (int j = 0; j < 2; j++) {
            int col = n0 + ncol + j * 16 + ccol;
            float badd = bias[col];
#pragma unroll
            for (int r = 0; r < 4; r++) {
                int row = m0 + mrow + i * 16 + crow + r;
                size_t idx = (size_t)row * N + col;
                if constexpr (EPI == 1) {
                    C[idx] = acc[i][j][r] + badd + rpre[i][j][r];
                } else {
                    C[idx] = C[idx] + acc[i][j][r] + badd;
                }
            }
        }
    }
}

// ---------------------------------------------------------------------------
// FF2 GEMM, 64x64 tile, BK=64 dbuf (r0-proven loop), SPLIT-K=2.
// r5 evidence: FF2 was grid-limited at 4 blocks/CU (Occ 36%) while 32 KB
// LDS allows 5.  Grid 2048 -> 5/CU; K-chain halved; epilogue = fp32
// atomicAdd (deletes the 16 MB C-read).  Mapping n0=(id&15), ks=(id>>4)&1,
// m0=(id>>5): id & id+16 share an XCD (16 % 8 == 0) so each n-panel and
// both k-splits of a tile resolve in one XCD's L2.  Bias added by ks==0.
// ---------------------------------------------------------------------------
__global__ __launch_bounds__(256) void ff2_s64(
    const unsigned short* __restrict__ A,   // M x K bf16
    const unsigned short* __restrict__ Bt,  // N x K bf16
    float* __restrict__ C,                  // fp32, atomic +=
    const float* __restrict__ bias,
    int M, int N, int K) {
    __shared__ unsigned short As[2][64 * 64];  // 16 KB
    __shared__ unsigned short Bs[2][64 * 64];  // 16 KB

    const int t = threadIdx.x;
    const int w = t >> 6, lane = t & 63;
    const int id = blockIdx.x;
    const int n0 = (id & 15) * 64;
    const int ks = (id >> 4) & 1;
    const int m0 = (id >> 5) * 64;
    const int khalf = K >> 1;
    const int kbeg = ks * khalf;

    const int srow = lane >> 3;
    const int sc = (lane & 7) ^ srow;
    const unsigned short* gA[2];
    const unsigned short* gB[2];
#pragma unroll
    for (int i = 0; i < 2; i++) {
        gA[i] = A + (size_t)(m0 + i * 32 + w * 8 + srow) * K + kbeg + sc * 8;
        gB[i] = Bt + (size_t)(n0 + i * 32 + w * 8 + srow) * K + kbeg + sc * 8;
    }

    int ph[2];
#pragma unroll
    for (int s = 0; s < 2; s++) ph[s] = ((s * 4 + (lane >> 4)) ^ (lane & 7)) * 8;
    const int mrow = (w >> 1) * 32, ncol = (w & 1) * 32;
    int abase[2], bbase[2];
#pragma unroll
    for (int i = 0; i < 2; i++) {
        abase[i] = (mrow + i * 16 + (lane & 15)) * 64;
        bbase[i] = (ncol + i * 16 + (lane & 15)) * 64;
    }

    f32x4 acc[2][2];
#pragma unroll
    for (int i = 0; i < 2; i++)
#pragma unroll
        for (int j = 0; j < 2; j++) acc[i][j] = (f32x4){0.f, 0.f, 0.f, 0.f};

#define STGF(b)                                                                \
    do {                                                                       \
        _Pragma("unroll") for (int i_ = 0; i_ < 2; i_++) {                     \
            GLOAD_LDS16(gA[i_], &As[b][(i_ * 32 + w * 8) * 64]);               \
            GLOAD_LDS16(gB[i_], &Bs[b][(i_ * 32 + w * 8) * 64]);               \
            gA[i_] += 64; gB[i_] += 64;                                        \
        }                                                                      \
    } while (0)

    STGF(0);
    const int nk = khalf >> 6;   // 32 K-steps per split
    for (int it = 0; it < nk; it++) {
        const int buf = it & 1;
        __syncthreads();
        if (it + 1 < nk) STGF(buf ^ 1);
#pragma unroll
        for (int s = 0; s < 2; s++) {
            bf16x8 af[2], bfr[2];
#pragma unroll
            for (int i = 0; i < 2; i++) {
                af[i] = *reinterpret_cast<const bf16x8*>(&As[buf][abase[i] + ph[s]]);
                bfr[i] = *reinterpret_cast<const bf16x8*>(&Bs[buf][bbase[i] + ph[s]]);
            }
#pragma unroll
            for (int i = 0; i < 2; i++)
#pragma unroll
                for (int j = 0; j < 2; j++)
                    acc[i][j] = __builtin_amdgcn_mfma_f32_16x16x32_bf16(
                        af[i], bfr[j], acc[i][j], 0, 0, 0);
        }
    }
#undef STGF

    const int ccol = lane & 15;
    const int crow = (lane >> 4) << 2;
#pragma unroll
    for (int i = 0; i < 2; i++) {
#pragma unroll
        for (int j = 0; j < 2; j++) {
            int col = n0 + ncol + j * 16 + ccol;
            float badd = ks == 0 ? bias[col] : 0.f;
#pragma unroll
            for (int r = 0; r < 4; r++) {
                int row = m0 + mrow + i * 16 + crow + r;
                size_t idx = (size_t)row * N + col;
                unsafeAtomicAdd(&C[idx], acc[i][j][r] + badd);
            }
        }
    }
}

// ---------------------------------------------------------------------------
// Fused QKV, BK=64 double-buffered (r0-proven): 768 blocks.
//   [0,512):  qk: m = (bid&31)*128 (same-m -> same XCD), n = (bid>>5)*128
//   [512,768): vT[1024][4096] = wvT @ lnO^T
// ---------------------------------------------------------------------------
__global__ __launch_bounds__(256) void qkv_gemm(
    const unsigned short* __restrict__ lnO,   // [4096][1024]
    const unsigned short* __restrict__ wqkT,  // [2048][1024]
    const unsigned short* __restrict__ wvT,   // [1024][1024]
    unsigned short* __restrict__ q,           // [4096][1024]
    unsigned short* __restrict__ kb,          // [4096][1024]
    unsigned short* __restrict__ vT) {        // [1024][4096]
    __shared__ unsigned short As[2][128 * 64];
    __shared__ unsigned short Bs[2][128 * 64];

    const int t = threadIdx.x;
    const int w = t >> 6, lane = t & 63;
    const int bid = blockIdx.x;
    const bool qk = bid < 512;

    const unsigned short *A, *Bt;
    int m0, n0, N;
    if (qk) {
        A = lnO; Bt = wqkT;
        m0 = (bid & 31) * 128; n0 = (bid >> 5) * 128; N = 2048;
    } else {
        int lb = bid - 512;
        A = wvT; Bt = lnO;
        m0 = (lb & 7) * 128; n0 = (lb >> 3) * 128; N = 4096;
    }
    const int K = 1024;

    const int srow = lane >> 3;
    const int sc = (lane & 7) ^ srow;
    const unsigned short* gA[4];
    const unsigned short* gB[4];
#pragma unroll
    for (int i = 0; i < 4; i++) {
        gA[i] = A + (size_t)(m0 + i * 32 + w * 8 + srow) * K + sc * 8;
        gB[i] = Bt + (size_t)(n0 + i * 32 + w * 8 + srow) * K + sc * 8;
    }

    const int mrow = (w >> 1) * 64, ncol = (w & 1) * 64;
    int ph[2];
#pragma unroll
    for (int s = 0; s < 2; s++) ph[s] = ((s * 4 + (lane >> 4)) ^ (lane & 7)) * 8;
    int abase[4], bbase[4];
#pragma unroll
    for (int i = 0; i < 4; i++) {
        abase[i] = (mrow + i * 16 + (lane & 15)) * 64;
        bbase[i] = (ncol + i * 16 + (lane & 15)) * 64;
    }

    f32x4 acc[4][4];
#pragma unroll
    for (int i = 0; i < 4; i++)
#pragma unroll
        for (int j = 0; j < 4; j++) acc[i][j] = (f32x4){0.f, 0.f, 0.f, 0.f};

#define STGQ(b)                                                                \
    do {                                                                       \
        _Pragma("unroll") for (int i_ = 0; i_ < 4; i_++) {                     \
            GLOAD_LDS16(gA[i_], &As[b][(i_ * 32 + w * 8) * 64]);               \
            GLOAD_LDS16(gB[i_], &Bs[b][(i_ * 32 + w * 8) * 64]);               \
            gA[i_] += 64; gB[i_] += 64;                                        \
        }                                                                      \
    } while (0)

    STGQ(0);
    const int nk = K >> 6;
    for (int it = 0; it < nk; it++) {
        const int buf = it & 1;
        __syncthreads();
        if (it + 1 < nk) STGQ(buf ^ 1);
#pragma unroll
        for (int s = 0; s < 2; s++) {
            bf16x8 af[4], bfr[4];
#pragma unroll
            for (int i = 0; i < 4; i++) {
                af[i] = *reinterpret_cast<const bf16x8*>(&As[buf][abase[i] + ph[s]]);
                bfr[i] = *reinterpret_cast<const bf16x8*>(&Bs[buf][bbase[i] + ph[s]]);
            }
#pragma unroll
            for (int i = 0; i < 4; i++)
#pragma unroll
                for (int j = 0; j < 4; j++)
                    acc[i][j] = __builtin_amdgcn_mfma_f32_16x16x32_bf16(
                        af[i], bfr[j], acc[i][j], 0, 0, 0);
        }
    }
#undef STGQ

    const int ccol = lane & 15;
    const int crow = (lane >> 4) << 2;
    unsigned short* dst;
    int nbase;
    if (qk) {
        dst = (n0 < 1024) ? q : kb;
        nbase = n0 & 1023;
    } else {
        dst = vT;
        nbase = n0;
    }
    const int ldc = qk ? 1024 : 4096;
#pragma unroll
    for (int i = 0; i < 4; i++) {
#pragma unroll
        for (int j = 0; j < 4; j++) {
            int col = nbase + ncol + j * 16 + ccol;
#pragma unroll
            for (int r = 0; r < 4; r++) {
                int row = m0 + mrow + i * 16 + crow + r;
                dst[(size_t)row * ldc + col] = f2bf(acc[i][j][r]);
            }
        }
    }
}

// ---------------------------------------------------------------------------
// MFMA causal flash attention v6+T5: swapped operands (lane owns one q-row),
// lsum lane-local, P via cvt_pk + b64 writes, PV swapped (packed O-stores),
// s_setprio(1) around both MFMA clusters (T5).
// Grid (bh=32, pair=16): same-bh blocks 32 apart -> same XCD L2 for K/V.
// ---------------------------------------------------------------------------
__global__ __launch_bounds__(256) void attn_mfma(
    const unsigned short* __restrict__ Q,   // [4096][1024]
    const unsigned short* __restrict__ K,   // [4096][1024]
    const unsigned short* __restrict__ Vt,  // [1024][4096]
    unsigned short* __restrict__ O) {       // [4096][1024]
    __shared__ unsigned short Ks[2][64 * 64];
    __shared__ unsigned short Vs[2][64 * 64];
    __shared__ unsigned short Ps[4][16 * 64];

    const int t = threadIdx.x;
    const int w = t >> 6, lane = t & 63;
    const int l15 = lane & 15, l4 = lane >> 4;
    const int bh = blockIdx.x;    // 0..31  (same-bh -> same XCD)
    const int b = bh >> 4, h = bh & 15;
    const int pair = blockIdx.y;  // 0..15

    const int sr = (w << 3) + (lane >> 3);   // 0..31
    const int sc = lane & 7;
    const int c = sc ^ (sr & 7);
    const unsigned short* kbase = K + ((size_t)(b * SEQ)) * EMB + h * HD;
    const unsigned short* vbase = Vt + ((size_t)(h * HD)) * (size_t)NTOK + (size_t)b * SEQ;
    unsigned short* Pw = &Ps[w][0];

#define STAGE(k0s, buf)                                                        \
    do {                                                                       \
        GLOAD_LDS16(kbase + (size_t)((k0s) + sr) * EMB + c * 8,                \
                    &Ks[buf][(w << 3) * 64]);                                  \
        GLOAD_LDS16(kbase + (size_t)((k0s) + sr + 32) * EMB + c * 8,           \
                    &Ks[buf][((w << 3) + 32) * 64]);                           \
        GLOAD_LDS16(vbase + (size_t)sr * NTOK + (k0s) + c * 8,                 \
                    &Vs[buf][(w << 3) * 64]);                                  \
        GLOAD_LDS16(vbase + (size_t)(sr + 32) * NTOK + (k0s) + c * 8,          \
                    &Vs[buf][((w << 3) + 32) * 64]);                           \
    } while (0)

    const float C1 = 0.125f * 1.4426950408889634f;  // 1/sqrt(64) * log2e
    const float C2 = 3.0f * 1.4426950408889634f;    // fixed max = 3

#pragma unroll
    for (int phase = 0; phase < 2; phase++) {
        const int qt = phase ? pair : (31 - pair);
        const int q0 = qt * 64;

        const unsigned short* qg =
            Q + ((size_t)(b * SEQ + q0 + w * 16 + l15)) * EMB + h * HD + l4 * 8;
        bf16x8 qf0 = *(const bf16x8*)qg;
        bf16x8 qf1 = *(const bf16x8*)(qg + 32);
        const int qrow = q0 + w * 16 + l15;   // this lane's single q-row

        float ls[4] = {0.f, 0.f, 0.f, 0.f};
        f32x4 Oacc[4];
#pragma unroll
        for (int j = 0; j < 4; j++) Oacc[j] = (f32x4){0.f, 0.f, 0.f, 0.f};

        const int ntiles = qt + 1;
        __syncthreads();
        STAGE(0, 0);
        for (int tile = 0; tile < ntiles; tile++) {
            const int k0 = tile * 64;
            const int buf = tile & 1;
            __syncthreads();
            if (tile + 1 < ntiles) STAGE(k0 + 64, buf ^ 1);

            // S^T[k][q]: lane holds q = qrow, k = k0 + 16j + 4*l4 + r
            f32x4 S[4];
#pragma unroll
            for (int j = 0; j < 4; j++) S[j] = (f32x4){0.f, 0.f, 0.f, 0.f};
            __builtin_amdgcn_s_setprio(1);
#pragma unroll
            for (int s = 0; s < 2; s++) {
                bf16x8 qf = s ? qf1 : qf0;
#pragma unroll
                for (int j = 0; j < 4; j++) {
                    int rk = 16 * j + l15;
                    int phys = (s * 4 + l4) ^ (rk & 7);
                    bf16x8 kf = *(const bf16x8*)&Ks[buf][rk * 64 + phys * 8];
                    S[j] = __builtin_amdgcn_mfma_f32_16x16x32_bf16(kf, qf, S[j], 0, 0, 0);
                }
            }
            __builtin_amdgcn_s_setprio(0);

            if (tile == ntiles - 1) {
#pragma unroll
                for (int j = 0; j < 4; j++)
#pragma unroll
                    for (int r = 0; r < 4; r++) {
                        float e = exp2f(S[j][r] * C1 - C2);
                        if (k0 + 16 * j + 4 * l4 + r > qrow) e = 0.f;
                        S[j][r] = e;
                    }
            } else {
#pragma unroll
                for (int j = 0; j < 4; j++)
#pragma unroll
                    for (int r = 0; r < 4; r++)
                        S[j][r] = exp2f(S[j][r] * C1 - C2);
            }

            // pack P[q][k] into LDS: b64 per j (k = 16j+4*l4 .. +3),
            // chunk-XOR swizzle by (q&7) -> conflict-light write & b128 read
#pragma unroll
            for (int j = 0; j < 4; j++) {
                ls[j] += S[j][0] + S[j][1] + S[j][2] + S[j][3];
                unsigned int lo = cvt_pk_bf16(S[j][0], S[j][1]);
                unsigned int hi = cvt_pk_bf16(S[j][2], S[j][3]);
                int chunk = (2 * j + (l4 >> 1)) ^ (l15 & 7);
                uint2 val; val.x = lo; val.y = hi;
                *reinterpret_cast<uint2*>(&Pw[l15 * 64 + chunk * 8 + (l4 & 1) * 4]) = val;
            }

            // O^T = V^T * P^T: lane holds q = qrow, d = 16j + 4*l4 + r
            __builtin_amdgcn_s_setprio(1);
#pragma unroll
            for (int s = 0; s < 2; s++) {
                int pch = (4 * s + l4) ^ (l15 & 7);
                bf16x8 pf = *(const bf16x8*)&Pw[l15 * 64 + pch * 8];
#pragma unroll
                for (int j = 0; j < 4; j++) {
                    int rv = 16 * j + l15;
                    int vph = (s * 4 + l4) ^ (rv & 7);
                    bf16x8 vf = *(const bf16x8*)&Vs[buf][rv * 64 + vph * 8];
                    Oacc[j] = __builtin_amdgcn_mfma_f32_16x16x32_bf16(vf, pf, Oacc[j], 0, 0, 0);
                }
            }
            __builtin_amdgcn_s_setprio(0);
        }

        float l = ls[0] + ls[1] + ls[2] + ls[3];
        l += __shfl_xor(l, 16, 64);
        l += __shfl_xor(l, 32, 64);
        float inv = 1.f / l;
        size_t rowb = (size_t)(b * SEQ + qrow) * EMB + h * HD;
#pragma unroll
        for (int j = 0; j < 4; j++) {
            unsigned int lo = cvt_pk_bf16(Oacc[j][0] * inv, Oacc[j][1] * inv);
            unsigned int hi = cvt_pk_bf16(Oacc[j][2] * inv, Oacc[j][3] * inv);
            uint2 val; val.x = lo; val.y = hi;
            *reinterpret_cast<uint2*>(&O[rowb + 16 * j + 4 * l4]) = val;
        }
    }
#undef STAGE
}

// ---------------------------------------------------------------------------
// launch
// ---------------------------------------------------------------------------
extern "C" void kernel_launch(void* const* d_in, const int* in_sizes, int n_in,
                              void* d_out, int out_size, void* d_ws, size_t ws_size,
                              hipStream_t stream) {
    const float* x     = (const float*)d_in[0];
    const float* w_q   = (const float*)d_in[1];
    const float* w_k   = (const float*)d_in[2];
    const float* w_v   = (const float*)d_in[3];
    const float* w_o   = (const float*)d_in[4];
    const float* b_o   = (const float*)d_in[5];
    const float* ln1s  = (const float*)d_in[6];
    const float* ln1b  = (const float*)d_in[7];
    const float* ln2s  = (const float*)d_in[8];
    const float* ln2b  = (const float*)d_in[9];
    const float* w_ff1 = (const float*)d_in[10];
    const float* b_ff1 = (const float*)d_in[11];
    const float* w_ff2 = (const float*)d_in[12];
    const float* b_ff2 = (const float*)d_in[13];
    float* out = (float*)d_out;

    char* p = (char*)d_ws;
    unsigned short* lnO  = (unsigned short*)p; p += (size_t)NTOK * EMB * 2;      // 8 MB
    unsigned short* q    = (unsigned short*)p; p += (size_t)NTOK * EMB * 2;
    unsigned short* kbuf = (unsigned short*)p; p += (size_t)NTOK * EMB * 2;
    unsigned short* vT   = (unsigned short*)p; p += (size_t)NTOK * EMB * 2;
    unsigned short* ctx  = (unsigned short*)p; p += (size_t)NTOK * EMB * 2;      // attn out, later LN2 out
    unsigned short* ff1a = (unsigned short*)p; p += (size_t)NTOK * FF_DIM * 2;   // 32 MB
    unsigned short* wqkT = (unsigned short*)p; p += (size_t)2 * EMB * EMB * 2;   // 4 MB
    unsigned short* wvT  = (unsigned short*)p; p += (size_t)EMB * EMB * 2;
    unsigned short* woT  = (unsigned short*)p; p += (size_t)EMB * EMB * 2;
    unsigned short* wf1T = (unsigned short*)p; p += (size_t)FF_DIM * EMB * 2;    // 8 MB
    unsigned short* wf2T = (unsigned short*)p; p += (size_t)EMB * FF_DIM * 2;    // 8 MB

    dim3 blk(256);
    dim3 gS64(NTOK / 64, EMB / 64);         // 64 m x 16 n = 1024 blocks
    dim3 gFF1(NTOK / 128, FF_DIM / 128);    // 32 m x 32 n = 1024
    dim3 gAttn(BATCH * HEADS, 16);          // bh x pair; same-bh -> same XCD

    // fused weight transpose+cast + LN1
    prep_kernel<<<3072 + NTOK, blk, 0, stream>>>(
        w_q, w_k, w_v, w_o, w_ff1, w_ff2,
        wqkT, wqkT + (size_t)EMB * EMB, wvT, woT, wf1T, wf2T,
        x, ln1s, ln1b, lnO);
    qkv_gemm<<<768, blk, 0, stream>>>(lnO, wqkT, wvT, q, kbuf, vT);
    attn_mfma<<<gAttn, blk, 0, stream>>>(q, kbuf, vT, ctx);
    // O-proj fused: out = x + b_o + ctx @ w_o   (64x64 tiles, 1024 blocks)
    mfma_gemm_s64<1><<<gS64, blk, 0, stream>>>(ctx, woT, out, b_o, x, NTOK, EMB, EMB);
    // LN2: out -> ctx (bf16)
    ln_kernel<<<NTOK, blk, 0, stream>>>(out, ln2s, ln2b, ctx);
    // FF1 + cheap gelu epilogue
    ff1_gemm<<<gFF1, blk, 0, stream>>>(ctx, wf1T, ff1a, b_ff1, NTOK, FF_DIM, EMB);
    // FF2 split-K=2, atomic epilogue: out += ff1a @ w_ff2 + b_ff2 (2048 blocks)
    ff2_s64<<<2048, blk, 0, stream>>>(ff1a, wf2T, out, b_ff2, NTOK, EMB, FF_DIM);
}

// Round 7
// 328.748 us; speedup vs baseline: 1.0354x; 1.0354x over previous
//
#include <hip/hip_runtime.h>
#include <math.h>

#define EMB 1024
#define HEADS 16
#define HD 64
#define FF_DIM 4096
#define SEQ 2048
#define BATCH 2
#define NTOK (BATCH * SEQ)   // 4096

typedef __bf16 bf16x8 __attribute__((ext_vector_type(8)));
typedef float f32x4 __attribute__((ext_vector_type(4)));

__device__ __forceinline__ unsigned short f2bf(float f) {
    union { float f; unsigned int u; } v; v.f = f;
    unsigned int r = v.u + 0x7fff + ((v.u >> 16) & 1);  // RNE
    return (unsigned short)(r >> 16);
}

// pack 2 fp32 -> 2 bf16 in one u32 (no builtin on gfx950; inline asm)
__device__ __forceinline__ unsigned int cvt_pk_bf16(float a, float b) {
    unsigned int r;
    asm("v_cvt_pk_bf16_f32 %0, %1, %2" : "=v"(r) : "v"(a), "v"(b));
    return r;
}

// gelu_tanh(x) = 0.5x(1+tanh(z)) = x*sigmoid(2z), z = c(x+0.044715x^3).
__device__ __forceinline__ float gelu_f(float x) {
    const float A = 1.5957691216057308f;   // 2c, c = sqrt(2/pi)
    const float B = 0.07135481282989427f;  // 2c*0.044715
    float zz = x * (A + B * x * x);
    return x * __builtin_amdgcn_rcpf(1.f + __expf(-zz));
}

#define GLOAD_LDS16(g, l)                                                      \
    __builtin_amdgcn_global_load_lds(                                          \
        (const __attribute__((address_space(1))) void*)(g),                    \
        (__attribute__((address_space(3))) void*)(l), 16, 0, 0)

// ---------------------------------------------------------------------------
// LayerNorm: one block per row of 1024, fp32 in -> bf16 out.
// float4 loads (16B/lane), ushort4 packed stores (G13).
// ---------------------------------------------------------------------------
__global__ __launch_bounds__(256) void ln_kernel(const float* __restrict__ x,
                                                 const float* __restrict__ scale,
                                                 const float* __restrict__ shift,
                                                 unsigned short* __restrict__ out) {
    int row = blockIdx.x;
    const float4* xr = (const float4*)(x + (size_t)row * EMB);
    int t = threadIdx.x;

    float4 v = xr[t];
    float s = v.x + v.y + v.z + v.w;
    float s2 = v.x * v.x + v.y * v.y + v.z * v.z + v.w * v.w;
    for (int o = 32; o > 0; o >>= 1) {
        s += __shfl_down(s, o, 64);
        s2 += __shfl_down(s2, o, 64);
    }
    __shared__ float red[4], red2[4];
    int wave = t >> 6;
    if ((t & 63) == 0) { red[wave] = s; red2[wave] = s2; }
    __syncthreads();
    if (t == 0) {
        float a = 0.f, b = 0.f;
#pragma unroll
        for (int i = 0; i < 4; i++) { a += red[i]; b += red2[i]; }
        red[0] = a; red2[0] = b;
    }
    __syncthreads();
    float mean = red[0] * (1.f / EMB);
    float var = red2[0] * (1.f / EMB) - mean * mean;
    float rstd = rsqrtf(var + 1e-5f);

    float4 sc = ((const float4*)scale)[t];
    float4 sh = ((const float4*)shift)[t];
    ushort4 o;
    o.x = f2bf(sc.x * (v.x - mean) * rstd + sh.x);
    o.y = f2bf(sc.y * (v.y - mean) * rstd + sh.y);
    o.z = f2bf(sc.z * (v.z - mean) * rstd + sh.z);
    o.w = f2bf(sc.w * (v.w - mean) * rstd + sh.w);
    ((ushort4*)(out + (size_t)row * EMB))[t] = o;
}

// ---------------------------------------------------------------------------
// Fused prep: blocks [0,3072) = weight transpose+cast (6 weights),
//             blocks [3072,7168) = LN1 row (x -> lnO bf16, float4 path).
// ---------------------------------------------------------------------------
__global__ __launch_bounds__(256) void prep_kernel(
    const float* __restrict__ w0, const float* __restrict__ w1,
    const float* __restrict__ w2, const float* __restrict__ w3,
    const float* __restrict__ w4, const float* __restrict__ w5,
    unsigned short* __restrict__ o0, unsigned short* __restrict__ o1,
    unsigned short* __restrict__ o2, unsigned short* __restrict__ o3,
    unsigned short* __restrict__ o4, unsigned short* __restrict__ o5,
    const float* __restrict__ x, const float* __restrict__ ln1s,
    const float* __restrict__ ln1b, unsigned short* __restrict__ lnO) {
    __shared__ float tile[64][65];
    __shared__ float red[4], red2[4];
    int id = blockIdx.x;
    int t = threadIdx.x;

    if (id >= 3072) {
        // ---- LN1 path ----
        int row = id - 3072;
        const float4* xr = (const float4*)(x + (size_t)row * EMB);
        float4 v = xr[t];
        float s = v.x + v.y + v.z + v.w;
        float s2 = v.x * v.x + v.y * v.y + v.z * v.z + v.w * v.w;
        for (int o = 32; o > 0; o >>= 1) {
            s += __shfl_down(s, o, 64);
            s2 += __shfl_down(s2, o, 64);
        }
        int wave = t >> 6;
        if ((t & 63) == 0) { red[wave] = s; red2[wave] = s2; }
        __syncthreads();
        if (t == 0) {
            float a = 0.f, b = 0.f;
#pragma unroll
            for (int i = 0; i < 4; i++) { a += red[i]; b += red2[i]; }
            red[0] = a; red2[0] = b;
        }
        __syncthreads();
        float mean = red[0] * (1.f / EMB);
        float var = red2[0] * (1.f / EMB) - mean * mean;
        float rstd = rsqrtf(var + 1e-5f);

        float4 sc = ((const float4*)ln1s)[t];
        float4 sh = ((const float4*)ln1b)[t];
        ushort4 o;
        o.x = f2bf(sc.x * (v.x - mean) * rstd + sh.x);
        o.y = f2bf(sc.y * (v.y - mean) * rstd + sh.y);
        o.z = f2bf(sc.z * (v.z - mean) * rstd + sh.z);
        o.w = f2bf(sc.w * (v.w - mean) * rstd + sh.w);
        ((ushort4*)(lnO + (size_t)row * EMB))[t] = o;
        return;
    }

    // ---- transpose+cast path ----
    const float* src; unsigned short* dst; int K, N, lid;
    if (id < 256)       { src = w0; dst = o0; K = 1024; N = 1024; lid = id; }
    else if (id < 512)  { src = w1; dst = o1; K = 1024; N = 1024; lid = id - 256; }
    else if (id < 768)  { src = w2; dst = o2; K = 1024; N = 1024; lid = id - 512; }
    else if (id < 1024) { src = w3; dst = o3; K = 1024; N = 1024; lid = id - 768; }
    else if (id < 2048) { src = w4; dst = o4; K = 1024; N = 4096; lid = id - 1024; }
    else                { src = w5; dst = o5; K = 4096; N = 1024; lid = id - 2048; }
    int tn = N >> 6;
    int k0 = (lid / tn) << 6, n0 = (lid % tn) << 6;
    int rr = t >> 6, cc = t & 63;
#pragma unroll
    for (int i = 0; i < 16; i++) {
        int r = i * 4 + rr;
        tile[r][cc] = src[(size_t)(k0 + r) * N + n0 + cc];
    }
    __syncthreads();
#pragma unroll
    for (int i = 0; i < 16; i++) {
        int r = i * 4 + rr;
        dst[(size_t)(n0 + r) * K + k0 + cc] = f2bf(tile[cc][r]);
    }
}

// ===========================================================================
// BK=64 staging geometry: LDS row = 64 elems (128 B) = 8 x 16B chunks.
// Physical chunk p of row r holds logical chunk p ^ (r & 7); fragment
// ds_read_b128 aliases 2-way (free). Per global_load_lds instr: 8 rows;
// lane l -> row base+(l>>3), logical chunk (l&7)^(l>>3).
//
// r6 lesson (FETCH evidence): the 2D x=m-fastest grid with FULL residency
// fetches the theoretical minimum (L3 serves all A re-reads because all
// blocks march K in sync). Every 1D/split-K/atomic variant fetched ~139 MB
// and lost. Keep {2D grid, full co-residency, RMW epilogue} invariant.
// ===========================================================================

// ---------------------------------------------------------------------------
// FF1 GEMM, 128x128 tile, BK=64 double-buffered (r0-proven).
// Epilogue: bf16 gelu(acc + bias[n]).
// ---------------------------------------------------------------------------
__global__ __launch_bounds__(256) void ff1_gemm(
    const unsigned short* __restrict__ A,   // M x K bf16
    const unsigned short* __restrict__ Bt,  // N x K bf16
    unsigned short* __restrict__ C,
    const float* __restrict__ bias,
    int M, int N, int K) {
    __shared__ unsigned short As[2][128 * 64];  // 32 KB
    __shared__ unsigned short Bs[2][128 * 64];  // 32 KB

    const int t = threadIdx.x;
    const int w = t >> 6, lane = t & 63;
    const int m0 = blockIdx.x * 128, n0 = blockIdx.y * 128;

    const int srow = lane >> 3;
    const int sc = (lane & 7) ^ srow;   // logical chunk (elems*8)
    const unsigned short* gA[4];
    const unsigned short* gB[4];
#pragma unroll
    for (int i = 0; i < 4; i++) {
        gA[i] = A + (size_t)(m0 + i * 32 + w * 8 + srow) * K + sc * 8;
        gB[i] = Bt + (size_t)(n0 + i * 32 + w * 8 + srow) * K + sc * 8;
    }

    const int mrow = (w >> 1) * 64, ncol = (w & 1) * 64;
    int ph[2];
#pragma unroll
    for (int s = 0; s < 2; s++) ph[s] = ((s * 4 + (lane >> 4)) ^ (lane & 7)) * 8;
    int abase[4], bbase[4];
#pragma unroll
    for (int i = 0; i < 4; i++) {
        abase[i] = (mrow + i * 16 + (lane & 15)) * 64;
        bbase[i] = (ncol + i * 16 + (lane & 15)) * 64;
    }

    f32x4 acc[4][4];
#pragma unroll
    for (int i = 0; i < 4; i++)
#pragma unroll
        for (int j = 0; j < 4; j++) acc[i][j] = (f32x4){0.f, 0.f, 0.f, 0.f};

#define STG1(b)                                                                \
    do {                                                                       \
        _Pragma("unroll") for (int i_ = 0; i_ < 4; i_++) {                     \
            GLOAD_LDS16(gA[i_], &As[b][(i_ * 32 + w * 8) * 64]);               \
            GLOAD_LDS16(gB[i_], &Bs[b][(i_ * 32 + w * 8) * 64]);               \
            gA[i_] += 64; gB[i_] += 64;                                        \
        }                                                                      \
    } while (0)

    STG1(0);
    const int nk = K >> 6;
    for (int it = 0; it < nk; it++) {
        const int buf = it & 1;
        __syncthreads();
        if (it + 1 < nk) STG1(buf ^ 1);
#pragma unroll
        for (int s = 0; s < 2; s++) {
            bf16x8 af[4], bfr[4];
#pragma unroll
            for (int i = 0; i < 4; i++) {
                af[i] = *reinterpret_cast<const bf16x8*>(&As[buf][abase[i] + ph[s]]);
                bfr[i] = *reinterpret_cast<const bf16x8*>(&Bs[buf][bbase[i] + ph[s]]);
            }
#pragma unroll
            for (int i = 0; i < 4; i++)
#pragma unroll
                for (int j = 0; j < 4; j++)
                    acc[i][j] = __builtin_amdgcn_mfma_f32_16x16x32_bf16(
                        af[i], bfr[j], acc[i][j], 0, 0, 0);
        }
    }
#undef STG1

    const int ccol = lane & 15;
    const int crow = (lane >> 4) << 2;
#pragma unroll
    for (int i = 0; i < 4; i++) {
#pragma unroll
        for (int j = 0; j < 4; j++) {
            int col = n0 + ncol + j * 16 + ccol;
            float badd = bias[col];
#pragma unroll
            for (int r = 0; r < 4; r++) {
                int row = m0 + mrow + i * 16 + crow + r;
                C[(size_t)row * N + col] = f2bf(gelu_f(acc[i][j][r] + badd));
            }
        }
    }
}

// ---------------------------------------------------------------------------
// N=1024 GEMM, 64x64 tile, BK=64 double-buffered, XCD mapping (x = m-tile).
// Grid (M/64, N/64) = 64x16 = 1024 blocks.  (O-proj only.)
// EPI 1: C = acc + bias[n] + resid (fp32); resid prefetched pre-K-loop.
// ---------------------------------------------------------------------------
template <int EPI>
__global__ __launch_bounds__(256) void mfma_gemm_s64(
    const unsigned short* __restrict__ A,   // M x K bf16
    const unsigned short* __restrict__ Bt,  // N x K bf16
    float* __restrict__ C,
    const float* __restrict__ bias,
    const float* __restrict__ resid,
    int M, int N, int K) {
    __shared__ unsigned short As[2][64 * 64];  // 16 KB
    __shared__ unsigned short Bs[2][64 * 64];  // 16 KB

    const int t = threadIdx.x;
    const int w = t >> 6, lane = t & 63;
    const int m0 = blockIdx.x * 64, n0 = blockIdx.y * 64;

    const int srow = lane >> 3;
    const int sc = (lane & 7) ^ srow;
    const unsigned short* gA[2];
    const unsigned short* gB[2];
#pragma unroll
    for (int i = 0; i < 2; i++) {
        gA[i] = A + (size_t)(m0 + i * 32 + w * 8 + srow) * K + sc * 8;
        gB[i] = Bt + (size_t)(n0 + i * 32 + w * 8 + srow) * K + sc * 8;
    }

    int ph[2];
#pragma unroll
    for (int s = 0; s < 2; s++) ph[s] = ((s * 4 + (lane >> 4)) ^ (lane & 7)) * 8;
    // wave tile 32x32: rows mrow..mrow+31, cols ncol..ncol+31
    const int mrow = (w >> 1) * 32, ncol = (w & 1) * 32;
    int abase[2], bbase[2];
#pragma unroll
    for (int i = 0; i < 2; i++) {
        abase[i] = (mrow + i * 16 + (lane & 15)) * 64;
        bbase[i] = (ncol + i * 16 + (lane & 15)) * 64;
    }

    const int ccol = lane & 15;
    const int crow = (lane >> 4) << 2;

    // prefetch resid tile into registers (EPI 1 only): hides the HBM read
    float rpre[2][2][4];
    if constexpr (EPI == 1) {
#pragma unroll
        for (int i = 0; i < 2; i++)
#pragma unroll
            for (int j = 0; j < 2; j++)
#pragma unroll
                for (int r = 0; r < 4; r++) {
                    int row = m0 + mrow + i * 16 + crow + r;
                    int col = n0 + ncol + j * 16 + ccol;
                    rpre[i][j][r] = resid[(size_t)row * N + col];
                }
    }

    f32x4 acc[2][2];
#pragma unroll
    for (int i = 0; i < 2; i++)
#pragma unroll
        for (int j = 0; j < 2; j++) acc[i][j] = (f32x4){0.f, 0.f, 0.f, 0.f};

#define STGS(b)                                                                \
    do {                                                                       \
        _Pragma("unroll") for (int i_ = 0; i_ < 2; i_++) {                     \
            GLOAD_LDS16(gA[i_], &As[b][(i_ * 32 + w * 8) * 64]);               \
            GLOAD_LDS16(gB[i_], &Bs[b][(i_ * 32 + w * 8) * 64]);               \
            gA[i_] += 64; gB[i_] += 64;                                        \
        }                                                                      \
    } while (0)

    STGS(0);
    const int nk = K >> 6;
    for (int it = 0; it < nk; it++) {
        const int buf = it & 1;
        __syncthreads();
        if (it + 1 < nk) STGS(buf ^ 1);
#pragma unroll
        for (int s = 0; s < 2; s++) {
            bf16x8 af[2], bfr[2];
#pragma unroll
            for (int i = 0; i < 2; i++) {
                af[i] = *reinterpret_cast<const bf16x8*>(&As[buf][abase[i] + ph[s]]);
                bfr[i] = *reinterpret_cast<const bf16x8*>(&Bs[buf][bbase[i] + ph[s]]);
            }
#pragma unroll
            for (int i = 0; i < 2; i++)
#pragma unroll
                for (int j = 0; j < 2; j++)
                    acc[i][j] = __builtin_amdgcn_mfma_f32_16x16x32_bf16(
                        af[i], bfr[j], acc[i][j], 0, 0, 0);
        }
    }
#undef STGS

#pragma unroll
    for (int i = 0; i < 2; i++) {
#pragma unroll
        for (int j = 0; j < 2; j++) {
            int col = n0 + ncol + j * 16 + ccol;
            float badd = bias[col];
#pragma unroll
            for (int r = 0; r < 4; r++) {
                int row = m0 + mrow + i * 16 + crow + r;
                size_t idx = (size_t)row * N + col;
                if constexpr (EPI == 1) {
                    C[idx] = acc[i][j][r] + badd + rpre[i][j][r];
                } else {
                    C[idx] = C[idx] + acc[i][j][r] + badd;
                }
            }
        }
    }
}

// ---------------------------------------------------------------------------
// FF2 GEMM v7: 128x64 tile, BK=64 dbuf, wave tile 64x32 (2Mx2N waves).
// Per s-step: 6 ds_read_b128 (4A+2B) feed 8 MFMA = 0.75 KB LDS-read/MFMA
// (64^2 tile was 1.0) — FF2 is LDS-read-bound, so -25% on the binding pipe.
// Preserves ALL anchor properties: 2D grid x=m fastest (32x16=512 blocks),
// LDS 48 KB -> 3 blocks/CU -> FULLY co-resident (512<768), one barrier per
// K-step, same swizzle, fp32 RMW epilogue (no atomics, no split-K).
// ---------------------------------------------------------------------------
__global__ __launch_bounds__(256) void ff2_gemm(
    const unsigned short* __restrict__ A,   // M x K bf16
    const unsigned short* __restrict__ Bt,  // N x K bf16
    float* __restrict__ C,                  // fp32, RMW +=
    const float* __restrict__ bias,
    int M, int N, int K) {
    __shared__ unsigned short As[2][128 * 64];  // 32 KB
    __shared__ unsigned short Bs[2][64 * 64];   // 16 KB

    const int t = threadIdx.x;
    const int w = t >> 6, lane = t & 63;
    const int l15 = lane & 15;
    const int m0 = blockIdx.x * 128, n0 = blockIdx.y * 64;

    const int srow = lane >> 3;
    const int sc = (lane & 7) ^ srow;
    const unsigned short* gA[4];
    const unsigned short* gB[2];
#pragma unroll
    for (int i = 0; i < 4; i++)
        gA[i] = A + (size_t)(m0 + i * 32 + w * 8 + srow) * K + sc * 8;
#pragma unroll
    for (int i = 0; i < 2; i++)
        gB[i] = Bt + (size_t)(n0 + i * 32 + w * 8 + srow) * K + sc * 8;

    int ph[2];
#pragma unroll
    for (int s = 0; s < 2; s++) ph[s] = ((s * 4 + (lane >> 4)) ^ (lane & 7)) * 8;
    // wave tile 64x32: rows mrow..mrow+63, cols ncol..ncol+31
    const int mrow = (w >> 1) * 64, ncol = (w & 1) * 32;
    int abase[4], bbase[2];
#pragma unroll
    for (int i = 0; i < 4; i++) abase[i] = (mrow + i * 16 + l15) * 64;
#pragma unroll
    for (int j = 0; j < 2; j++) bbase[j] = (ncol + j * 16 + l15) * 64;

    f32x4 acc[4][2];
#pragma unroll
    for (int i = 0; i < 4; i++)
#pragma unroll
        for (int j = 0; j < 2; j++) acc[i][j] = (f32x4){0.f, 0.f, 0.f, 0.f};

#define STGF(b)                                                                \
    do {                                                                       \
        _Pragma("unroll") for (int i_ = 0; i_ < 4; i_++) {                     \
            GLOAD_LDS16(gA[i_], &As[b][(i_ * 32 + w * 8) * 64]);               \
            gA[i_] += 64;                                                      \
        }                                                                      \
        _Pragma("unroll") for (int i_ = 0; i_ < 2; i_++) {                     \
            GLOAD_LDS16(gB[i_], &Bs[b][(i_ * 32 + w * 8) * 64]);               \
            gB[i_] += 64;                                                      \
        }                                                                      \
    } while (0)

    STGF(0);
    const int nk = K >> 6;
    for (int it = 0; it < nk; it++) {
        const int buf = it & 1;
        __syncthreads();
        if (it + 1 < nk) STGF(buf ^ 1);
#pragma unroll
        for (int s = 0; s < 2; s++) {
            bf16x8 af[4], bfr[2];
#pragma unroll
            for (int i = 0; i < 4; i++)
                af[i] = *reinterpret_cast<const bf16x8*>(&As[buf][abase[i] + ph[s]]);
#pragma unroll
            for (int j = 0; j < 2; j++)
                bfr[j] = *reinterpret_cast<const bf16x8*>(&Bs[buf][bbase[j] + ph[s]]);
#pragma unroll
            for (int i = 0; i < 4; i++)
#pragma unroll
                for (int j = 0; j < 2; j++)
                    acc[i][j] = __builtin_amdgcn_mfma_f32_16x16x32_bf16(
                        af[i], bfr[j], acc[i][j], 0, 0, 0);
        }
    }
#undef STGF

    const int ccol = l15;
    const int crow = (lane >> 4) << 2;
#pragma unroll
    for (int i = 0; i < 4; i++) {
#pragma unroll
        for (int j = 0; j < 2; j++) {
            int col = n0 + ncol + j * 16 + ccol;
            float badd = bias[col];
#pragma unroll
            for (int r = 0; r < 4; r++) {
                int row = m0 + mrow + i * 16 + crow + r;
                size_t idx = (size_t)row * N + col;
                C[idx] = C[idx] + acc[i][j][r] + badd;
            }
        }
    }
}

// ---------------------------------------------------------------------------
// Fused QKV, BK=64 double-buffered (r0-proven): 768 blocks.
//   [0,512):  qk: m = (bid&31)*128 (same-m -> same XCD), n = (bid>>5)*128
//   [512,768): vT[1024][4096] = wvT @ lnO^T
// ---------------------------------------------------------------------------
__global__ __launch_bounds__(256) void qkv_gemm(
    const unsigned short* __restrict__ lnO,   // [4096][1024]
    const unsigned short* __restrict__ wqkT,  // [2048][1024]
    const unsigned short* __restrict__ wvT,   // [1024][1024]
    unsigned short* __restrict__ q,           // [4096][1024]
    unsigned short* __restrict__ kb,          // [4096][1024]
    unsigned short* __restrict__ vT) {        // [1024][4096]
    __shared__ unsigned short As[2][128 * 64];
    __shared__ unsigned short Bs[2][128 * 64];

    const int t = threadIdx.x;
    const int w = t >> 6, lane = t & 63;
    const int bid = blockIdx.x;
    const bool qk = bid < 512;

    const unsigned short *A, *Bt;
    int m0, n0, N;
    if (qk) {
        A = lnO; Bt = wqkT;
        m0 = (bid & 31) * 128; n0 = (bid >> 5) * 128; N = 2048;
    } else {
        int lb = bid - 512;
        A = wvT; Bt = lnO;
        m0 = (lb & 7) * 128; n0 = (lb >> 3) * 128; N = 4096;
    }
    const int K = 1024;

    const int srow = lane >> 3;
    const int sc = (lane & 7) ^ srow;
    const unsigned short* gA[4];
    const unsigned short* gB[4];
#pragma unroll
    for (int i = 0; i < 4; i++) {
        gA[i] = A + (size_t)(m0 + i * 32 + w * 8 + srow) * K + sc * 8;
        gB[i] = Bt + (size_t)(n0 + i * 32 + w * 8 + srow) * K + sc * 8;
    }

    const int mrow = (w >> 1) * 64, ncol = (w & 1) * 64;
    int ph[2];
#pragma unroll
    for (int s = 0; s < 2; s++) ph[s] = ((s * 4 + (lane >> 4)) ^ (lane & 7)) * 8;
    int abase[4], bbase[4];
#pragma unroll
    for (int i = 0; i < 4; i++) {
        abase[i] = (mrow + i * 16 + (lane & 15)) * 64;
        bbase[i] = (ncol + i * 16 + (lane & 15)) * 64;
    }

    f32x4 acc[4][4];
#pragma unroll
    for (int i = 0; i < 4; i++)
#pragma unroll
        for (int j = 0; j < 4; j++) acc[i][j] = (f32x4){0.f, 0.f, 0.f, 0.f};

#define STGQ(b)                                                                \
    do {                                                                       \
        _Pragma("unroll") for (int i_ = 0; i_ < 4; i_++) {                     \
            GLOAD_LDS16(gA[i_], &As[b][(i_ * 32 + w * 8) * 64]);               \
            GLOAD_LDS16(gB[i_], &Bs[b][(i_ * 32 + w * 8) * 64]);               \
            gA[i_] += 64; gB[i_] += 64;                                        \
        }                                                                      \
    } while (0)

    STGQ(0);
    const int nk = K >> 6;
    for (int it = 0; it < nk; it++) {
        const int buf = it & 1;
        __syncthreads();
        if (it + 1 < nk) STGQ(buf ^ 1);
#pragma unroll
        for (int s = 0; s < 2; s++) {
            bf16x8 af[4], bfr[4];
#pragma unroll
            for (int i = 0; i < 4; i++) {
                af[i] = *reinterpret_cast<const bf16x8*>(&As[buf][abase[i] + ph[s]]);
                bfr[i] = *reinterpret_cast<const bf16x8*>(&Bs[buf][bbase[i] + ph[s]]);
            }
#pragma unroll
            for (int i = 0; i < 4; i++)
#pragma unroll
                for (int j = 0; j < 4; j++)
                    acc[i][j] = __builtin_amdgcn_mfma_f32_16x16x32_bf16(
                        af[i], bfr[j], acc[i][j], 0, 0, 0);
        }
    }
#undef STGQ

    const int ccol = lane & 15;
    const int crow = (lane >> 4) << 2;
    unsigned short* dst;
    int nbase;
    if (qk) {
        dst = (n0 < 1024) ? q : kb;
        nbase = n0 & 1023;
    } else {
        dst = vT;
        nbase = n0;
    }
    const int ldc = qk ? 1024 : 4096;
#pragma unroll
    for (int i = 0; i < 4; i++) {
#pragma unroll
        for (int j = 0; j < 4; j++) {
            int col = nbase + ncol + j * 16 + ccol;
#pragma unroll
            for (int r = 0; r < 4; r++) {
                int row = m0 + mrow + i * 16 + crow + r;
                dst[(size_t)row * ldc + col] = f2bf(acc[i][j][r]);
            }
        }
    }
}

// ---------------------------------------------------------------------------
// MFMA causal flash attention v6+T5: swapped operands (lane owns one q-row),
// lsum lane-local, P via cvt_pk + b64 writes, PV swapped (packed O-stores),
// s_setprio(1) around both MFMA clusters (T5).
// Grid (bh=32, pair=16): same-bh blocks 32 apart -> same XCD L2 for K/V.
// ---------------------------------------------------------------------------
__global__ __launch_bounds__(256) void attn_mfma(
    const unsigned short* __restrict__ Q,   // [4096][1024]
    const unsigned short* __restrict__ K,   // [4096][1024]
    const unsigned short* __restrict__ Vt,  // [1024][4096]
    unsigned short* __restrict__ O) {       // [4096][1024]
    __shared__ unsigned short Ks[2][64 * 64];
    __shared__ unsigned short Vs[2][64 * 64];
    __shared__ unsigned short Ps[4][16 * 64];

    const int t = threadIdx.x;
    const int w = t >> 6, lane = t & 63;
    const int l15 = lane & 15, l4 = lane >> 4;
    const int bh = blockIdx.x;    // 0..31  (same-bh -> same XCD)
    const int b = bh >> 4, h = bh & 15;
    const int pair = blockIdx.y;  // 0..15

    const int sr = (w << 3) + (lane >> 3);   // 0..31
    const int sc = lane & 7;
    const int c = sc ^ (sr & 7);
    const unsigned short* kbase = K + ((size_t)(b * SEQ)) * EMB + h * HD;
    const unsigned short* vbase = Vt + ((size_t)(h * HD)) * (size_t)NTOK + (size_t)b * SEQ;
    unsigned short* Pw = &Ps[w][0];

#define STAGE(k0s, buf)                                                        \
    do {                                                                       \
        GLOAD_LDS16(kbase + (size_t)((k0s) + sr) * EMB + c * 8,                \
                    &Ks[buf][(w << 3) * 64]);                                  \
        GLOAD_LDS16(kbase + (size_t)((k0s) + sr + 32) * EMB + c * 8,           \
                    &Ks[buf][((w << 3) + 32) * 64]);                           \
        GLOAD_LDS16(vbase + (size_t)sr * NTOK + (k0s) + c * 8,                 \
                    &Vs[buf][(w << 3) * 64]);                                  \
        GLOAD_LDS16(vbase + (size_t)(sr + 32) * NTOK + (k0s) + c * 8,          \
                    &Vs[buf][((w << 3) + 32) * 64]);                           \
    } while (0)

    const float C1 = 0.125f * 1.4426950408889634f;  // 1/sqrt(64) * log2e
    const float C2 = 3.0f * 1.4426950408889634f;    // fixed max = 3

#pragma unroll
    for (int phase = 0; phase < 2; phase++) {
        const int qt = phase ? pair : (31 - pair);
        const int q0 = qt * 64;

        const unsigned short* qg =
            Q + ((size_t)(b * SEQ + q0 + w * 16 + l15)) * EMB + h * HD + l4 * 8;
        bf16x8 qf0 = *(const bf16x8*)qg;
        bf16x8 qf1 = *(const bf16x8*)(qg + 32);
        const int qrow = q0 + w * 16 + l15;   // this lane's single q-row

        float ls[4] = {0.f, 0.f, 0.f, 0.f};
        f32x4 Oacc[4];
#pragma unroll
        for (int j = 0; j < 4; j++) Oacc[j] = (f32x4){0.f, 0.f, 0.f, 0.f};

        const int ntiles = qt + 1;
        __syncthreads();
        STAGE(0, 0);
        for (int tile = 0; tile < ntiles; tile++) {
            const int k0 = tile * 64;
            const int buf = tile & 1;
            __syncthreads();
            if (tile + 1 < ntiles) STAGE(k0 + 64, buf ^ 1);

            // S^T[k][q]: lane holds q = qrow, k = k0 + 16j + 4*l4 + r
            f32x4 S[4];
#pragma unroll
            for (int j = 0; j < 4; j++) S[j] = (f32x4){0.f, 0.f, 0.f, 0.f};
            __builtin_amdgcn_s_setprio(1);
#pragma unroll
            for (int s = 0; s < 2; s++) {
                bf16x8 qf = s ? qf1 : qf0;
#pragma unroll
                for (int j = 0; j < 4; j++) {
                    int rk = 16 * j + l15;
                    int phys = (s * 4 + l4) ^ (rk & 7);
                    bf16x8 kf = *(const bf16x8*)&Ks[buf][rk * 64 + phys * 8];
                    S[j] = __builtin_amdgcn_mfma_f32_16x16x32_bf16(kf, qf, S[j], 0, 0, 0);
                }
            }
            __builtin_amdgcn_s_setprio(0);

            if (tile == ntiles - 1) {
#pragma unroll
                for (int j = 0; j < 4; j++)
#pragma unroll
                    for (int r = 0; r < 4; r++) {
                        float e = exp2f(S[j][r] * C1 - C2);
                        if (k0 + 16 * j + 4 * l4 + r > qrow) e = 0.f;
                        S[j][r] = e;
                    }
            } else {
#pragma unroll
                for (int j = 0; j < 4; j++)
#pragma unroll
                    for (int r = 0; r < 4; r++)
                        S[j][r] = exp2f(S[j][r] * C1 - C2);
            }

            // pack P[q][k] into LDS: b64 per j (k = 16j+4*l4 .. +3),
            // chunk-XOR swizzle by (q&7) -> conflict-light write & b128 read
#pragma unroll
            for (int j = 0; j < 4; j++) {
                ls[j] += S[j][0] + S[j][1] + S[j][2] + S[j][3];
                unsigned int lo = cvt_pk_bf16(S[j][0], S[j][1]);
                unsigned int hi = cvt_pk_bf16(S[j][2], S[j][3]);
                int chunk = (2 * j + (l4 >> 1)) ^ (l15 & 7);
                uint2 val; val.x = lo; val.y = hi;
                *reinterpret_cast<uint2*>(&Pw[l15 * 64 + chunk * 8 + (l4 & 1) * 4]) = val;
            }

            // O^T = V^T * P^T: lane holds q = qrow, d = 16j + 4*l4 + r
            __builtin_amdgcn_s_setprio(1);
#pragma unroll
            for (int s = 0; s < 2; s++) {
                int pch = (4 * s + l4) ^ (l15 & 7);
                bf16x8 pf = *(const bf16x8*)&Pw[l15 * 64 + pch * 8];
#pragma unroll
                for (int j = 0; j < 4; j++) {
                    int rv = 16 * j + l15;
                    int vph = (s * 4 + l4) ^ (rv & 7);
                    bf16x8 vf = *(const bf16x8*)&Vs[buf][rv * 64 + vph * 8];
                    Oacc[j] = __builtin_amdgcn_mfma_f32_16x16x32_bf16(vf, pf, Oacc[j], 0, 0, 0);
                }
            }
            __builtin_amdgcn_s_setprio(0);
        }

        float l = ls[0] + ls[1] + ls[2] + ls[3];
        l += __shfl_xor(l, 16, 64);
        l += __shfl_xor(l, 32, 64);
        float inv = 1.f / l;
        size_t rowb = (size_t)(b * SEQ + qrow) * EMB + h * HD;
#pragma unroll
        for (int j = 0; j < 4; j++) {
            unsigned int lo = cvt_pk_bf16(Oacc[j][0] * inv, Oacc[j][1] * inv);
            unsigned int hi = cvt_pk_bf16(Oacc[j][2] * inv, Oacc[j][3] * inv);
            uint2 val; val.x = lo; val.y = hi;
            *reinterpret_cast<uint2*>(&O[rowb + 16 * j + 4 * l4]) = val;
        }
    }
#undef STAGE
}

// ---------------------------------------------------------------------------
// launch
// ---------------------------------------------------------------------------
extern "C" void kernel_launch(void* const* d_in, const int* in_sizes, int n_in,
                              void* d_out, int out_size, void* d_ws, size_t ws_size,
                              hipStream_t stream) {
    const float* x     = (const float*)d_in[0];
    const float* w_q   = (const float*)d_in[1];
    const float* w_k   = (const float*)d_in[2];
    const float* w_v   = (const float*)d_in[3];
    const float* w_o   = (const float*)d_in[4];
    const float* b_o   = (const float*)d_in[5];
    const float* ln1s  = (const float*)d_in[6];
    const float* ln1b  = (const float*)d_in[7];
    const float* ln2s  = (const float*)d_in[8];
    const float* ln2b  = (const float*)d_in[9];
    const float* w_ff1 = (const float*)d_in[10];
    const float* b_ff1 = (const float*)d_in[11];
    const float* w_ff2 = (const float*)d_in[12];
    const float* b_ff2 = (const float*)d_in[13];
    float* out = (float*)d_out;

    char* p = (char*)d_ws;
    unsigned short* lnO  = (unsigned short*)p; p += (size_t)NTOK * EMB * 2;      // 8 MB
    unsigned short* q    = (unsigned short*)p; p += (size_t)NTOK * EMB * 2;
    unsigned short* kbuf = (unsigned short*)p; p += (size_t)NTOK * EMB * 2;
    unsigned short* vT   = (unsigned short*)p; p += (size_t)NTOK * EMB * 2;
    unsigned short* ctx  = (unsigned short*)p; p += (size_t)NTOK * EMB * 2;      // attn out, later LN2 out
    unsigned short* ff1a = (unsigned short*)p; p += (size_t)NTOK * FF_DIM * 2;   // 32 MB
    unsigned short* wqkT = (unsigned short*)p; p += (size_t)2 * EMB * EMB * 2;   // 4 MB
    unsigned short* wvT  = (unsigned short*)p; p += (size_t)EMB * EMB * 2;
    unsigned short* woT  = (unsigned short*)p; p += (size_t)EMB * EMB * 2;
    unsigned short* wf1T = (unsigned short*)p; p += (size_t)FF_DIM * EMB * 2;    // 8 MB
    unsigned short* wf2T = (unsigned short*)p; p += (size_t)EMB * FF_DIM * 2;    // 8 MB

    dim3 blk(256);
    dim3 gS64(NTOK / 64, EMB / 64);         // 64 m x 16 n = 1024 blocks
    dim3 gFF1(NTOK / 128, FF_DIM / 128);    // 32 m x 32 n = 1024
    dim3 gFF2(NTOK / 128, EMB / 64);        // 32 m x 16 n = 512 blocks (3/CU cap, fully resident)
    dim3 gAttn(BATCH * HEADS, 16);          // bh x pair; same-bh -> same XCD

    // fused weight transpose+cast + LN1
    prep_kernel<<<3072 + NTOK, blk, 0, stream>>>(
        w_q, w_k, w_v, w_o, w_ff1, w_ff2,
        wqkT, wqkT + (size_t)EMB * EMB, wvT, woT, wf1T, wf2T,
        x, ln1s, ln1b, lnO);
    qkv_gemm<<<768, blk, 0, stream>>>(lnO, wqkT, wvT, q, kbuf, vT);
    attn_mfma<<<gAttn, blk, 0, stream>>>(q, kbuf, vT, ctx);
    // O-proj fused: out = x + b_o + ctx @ w_o   (64x64 tiles, 1024 blocks)
    mfma_gemm_s64<1><<<gS64, blk, 0, stream>>>(ctx, woT, out, b_o, x, NTOK, EMB, EMB);
    // LN2: out -> ctx (bf16)
    ln_kernel<<<NTOK, blk, 0, stream>>>(out, ln2s, ln2b, ctx);
    // FF1 + cheap gelu epilogue
    ff1_gemm<<<gFF1, blk, 0, stream>>>(ctx, wf1T, ff1a, b_ff1, NTOK, FF_DIM, EMB);
    // FF2 fused RMW: out += ff1a @ w_ff2 + b_ff2  (128x64 tiles, 512 blocks)
    ff2_gemm<<<gFF2, blk, 0, stream>>>(ff1a, wf2T, out, b_ff2, NTOK, EMB, FF_DIM);
}

// Round 8
// 319.369 us; speedup vs baseline: 1.0658x; 1.0294x over previous
//
#include <hip/hip_runtime.h>
#include <math.h>

#define EMB 1024
#define HEADS 16
#define HD 64
#define FF_DIM 4096
#define SEQ 2048
#define BATCH 2
#define NTOK (BATCH * SEQ)   // 4096

typedef __bf16 bf16x8 __attribute__((ext_vector_type(8)));
typedef float f32x4 __attribute__((ext_vector_type(4)));

__device__ __forceinline__ unsigned short f2bf(float f) {
    union { float f; unsigned int u; } v; v.f = f;
    unsigned int r = v.u + 0x7fff + ((v.u >> 16) & 1);  // RNE
    return (unsigned short)(r >> 16);
}

// pack 2 fp32 -> 2 bf16 in one u32 (no builtin on gfx950; inline asm)
__device__ __forceinline__ unsigned int cvt_pk_bf16(float a, float b) {
    unsigned int r;
    asm("v_cvt_pk_bf16_f32 %0, %1, %2" : "=v"(r) : "v"(a), "v"(b));
    return r;
}

// gelu_tanh(x) = 0.5x(1+tanh(z)) = x*sigmoid(2z), z = c(x+0.044715x^3).
__device__ __forceinline__ float gelu_f(float x) {
    const float A = 1.5957691216057308f;   // 2c, c = sqrt(2/pi)
    const float B = 0.07135481282989427f;  // 2c*0.044715
    float zz = x * (A + B * x * x);
    return x * __builtin_amdgcn_rcpf(1.f + __expf(-zz));
}

#define GLOAD_LDS16(g, l)                                                      \
    __builtin_amdgcn_global_load_lds(                                          \
        (const __attribute__((address_space(1))) void*)(g),                    \
        (__attribute__((address_space(3))) void*)(l), 16, 0, 0)

// ---------------------------------------------------------------------------
// LayerNorm: one block per row of 1024, fp32 in -> bf16 out.
// float4 loads (16B/lane), ushort4 packed stores (G13).
// ---------------------------------------------------------------------------
__global__ __launch_bounds__(256) void ln_kernel(const float* __restrict__ x,
                                                 const float* __restrict__ scale,
                                                 const float* __restrict__ shift,
                                                 unsigned short* __restrict__ out) {
    int row = blockIdx.x;
    const float4* xr = (const float4*)(x + (size_t)row * EMB);
    int t = threadIdx.x;

    float4 v = xr[t];
    float s = v.x + v.y + v.z + v.w;
    float s2 = v.x * v.x + v.y * v.y + v.z * v.z + v.w * v.w;
    for (int o = 32; o > 0; o >>= 1) {
        s += __shfl_down(s, o, 64);
        s2 += __shfl_down(s2, o, 64);
    }
    __shared__ float red[4], red2[4];
    int wave = t >> 6;
    if ((t & 63) == 0) { red[wave] = s; red2[wave] = s2; }
    __syncthreads();
    if (t == 0) {
        float a = 0.f, b = 0.f;
#pragma unroll
        for (int i = 0; i < 4; i++) { a += red[i]; b += red2[i]; }
        red[0] = a; red2[0] = b;
    }
    __syncthreads();
    float mean = red[0] * (1.f / EMB);
    float var = red2[0] * (1.f / EMB) - mean * mean;
    float rstd = rsqrtf(var + 1e-5f);

    float4 sc = ((const float4*)scale)[t];
    float4 sh = ((const float4*)shift)[t];
    ushort4 o;
    o.x = f2bf(sc.x * (v.x - mean) * rstd + sh.x);
    o.y = f2bf(sc.y * (v.y - mean) * rstd + sh.y);
    o.z = f2bf(sc.z * (v.z - mean) * rstd + sh.z);
    o.w = f2bf(sc.w * (v.w - mean) * rstd + sh.w);
    ((ushort4*)(out + (size_t)row * EMB))[t] = o;
}

// ---------------------------------------------------------------------------
// Fused prep: blocks [0,3072) = weight transpose+cast (6 weights),
//             blocks [3072,7168) = LN1 row (x -> lnO bf16, float4 path).
// ---------------------------------------------------------------------------
__global__ __launch_bounds__(256) void prep_kernel(
    const float* __restrict__ w0, const float* __restrict__ w1,
    const float* __restrict__ w2, const float* __restrict__ w3,
    const float* __restrict__ w4, const float* __restrict__ w5,
    unsigned short* __restrict__ o0, unsigned short* __restrict__ o1,
    unsigned short* __restrict__ o2, unsigned short* __restrict__ o3,
    unsigned short* __restrict__ o4, unsigned short* __restrict__ o5,
    const float* __restrict__ x, const float* __restrict__ ln1s,
    const float* __restrict__ ln1b, unsigned short* __restrict__ lnO) {
    __shared__ float tile[64][65];
    __shared__ float red[4], red2[4];
    int id = blockIdx.x;
    int t = threadIdx.x;

    if (id >= 3072) {
        // ---- LN1 path ----
        int row = id - 3072;
        const float4* xr = (const float4*)(x + (size_t)row * EMB);
        float4 v = xr[t];
        float s = v.x + v.y + v.z + v.w;
        float s2 = v.x * v.x + v.y * v.y + v.z * v.z + v.w * v.w;
        for (int o = 32; o > 0; o >>= 1) {
            s += __shfl_down(s, o, 64);
            s2 += __shfl_down(s2, o, 64);
        }
        int wave = t >> 6;
        if ((t & 63) == 0) { red[wave] = s; red2[wave] = s2; }
        __syncthreads();
        if (t == 0) {
            float a = 0.f, b = 0.f;
#pragma unroll
            for (int i = 0; i < 4; i++) { a += red[i]; b += red2[i]; }
            red[0] = a; red2[0] = b;
        }
        __syncthreads();
        float mean = red[0] * (1.f / EMB);
        float var = red2[0] * (1.f / EMB) - mean * mean;
        float rstd = rsqrtf(var + 1e-5f);

        float4 sc = ((const float4*)ln1s)[t];
        float4 sh = ((const float4*)ln1b)[t];
        ushort4 o;
        o.x = f2bf(sc.x * (v.x - mean) * rstd + sh.x);
        o.y = f2bf(sc.y * (v.y - mean) * rstd + sh.y);
        o.z = f2bf(sc.z * (v.z - mean) * rstd + sh.z);
        o.w = f2bf(sc.w * (v.w - mean) * rstd + sh.w);
        ((ushort4*)(lnO + (size_t)row * EMB))[t] = o;
        return;
    }

    // ---- transpose+cast path ----
    const float* src; unsigned short* dst; int K, N, lid;
    if (id < 256)       { src = w0; dst = o0; K = 1024; N = 1024; lid = id; }
    else if (id < 512)  { src = w1; dst = o1; K = 1024; N = 1024; lid = id - 256; }
    else if (id < 768)  { src = w2; dst = o2; K = 1024; N = 1024; lid = id - 512; }
    else if (id < 1024) { src = w3; dst = o3; K = 1024; N = 1024; lid = id - 768; }
    else if (id < 2048) { src = w4; dst = o4; K = 1024; N = 4096; lid = id - 1024; }
    else                { src = w5; dst = o5; K = 4096; N = 1024; lid = id - 2048; }
    int tn = N >> 6;
    int k0 = (lid / tn) << 6, n0 = (lid % tn) << 6;
    int rr = t >> 6, cc = t & 63;
#pragma unroll
    for (int i = 0; i < 16; i++) {
        int r = i * 4 + rr;
        tile[r][cc] = src[(size_t)(k0 + r) * N + n0 + cc];
    }
    __syncthreads();
#pragma unroll
    for (int i = 0; i < 16; i++) {
        int r = i * 4 + rr;
        dst[(size_t)(n0 + r) * K + k0 + cc] = f2bf(tile[cc][r]);
    }
}

// ===========================================================================
// BK=64 staging geometry: LDS row = 64 elems (128 B) = 8 x 16B chunks.
// Physical chunk p of row r holds logical chunk p ^ (r & 7); fragment
// ds_read_b128 aliases 2-way (free). Per global_load_lds instr: 8 rows;
// lane l -> row base+(l>>3), logical chunk (l&7)^(l>>3).
//
// FF2 invariants established r1-r7 (each violated once, each lost):
// {64^2 tile, BK=64 dbuf, 1024-block 2D x=m grid, FULL 4/CU co-residency,
//  RMW epilogue}. r8 keeps all of them and attacks the one untested cost:
// the __syncthreads vmcnt(0) drain (T4 counted-vmcnt, depth-2 prefetch).
// ===========================================================================

// ---------------------------------------------------------------------------
// FF1 GEMM, 128x128 tile, BK=64 double-buffered (r0-proven).
// Epilogue: bf16 gelu(acc + bias[n]).
// ---------------------------------------------------------------------------
__global__ __launch_bounds__(256) void ff1_gemm(
    const unsigned short* __restrict__ A,   // M x K bf16
    const unsigned short* __restrict__ Bt,  // N x K bf16
    unsigned short* __restrict__ C,
    const float* __restrict__ bias,
    int M, int N, int K) {
    __shared__ unsigned short As[2][128 * 64];  // 32 KB
    __shared__ unsigned short Bs[2][128 * 64];  // 32 KB

    const int t = threadIdx.x;
    const int w = t >> 6, lane = t & 63;
    const int m0 = blockIdx.x * 128, n0 = blockIdx.y * 128;

    const int srow = lane >> 3;
    const int sc = (lane & 7) ^ srow;   // logical chunk (elems*8)
    const unsigned short* gA[4];
    const unsigned short* gB[4];
#pragma unroll
    for (int i = 0; i < 4; i++) {
        gA[i] = A + (size_t)(m0 + i * 32 + w * 8 + srow) * K + sc * 8;
        gB[i] = Bt + (size_t)(n0 + i * 32 + w * 8 + srow) * K + sc * 8;
    }

    const int mrow = (w >> 1) * 64, ncol = (w & 1) * 64;
    int ph[2];
#pragma unroll
    for (int s = 0; s < 2; s++) ph[s] = ((s * 4 + (lane >> 4)) ^ (lane & 7)) * 8;
    int abase[4], bbase[4];
#pragma unroll
    for (int i = 0; i < 4; i++) {
        abase[i] = (mrow + i * 16 + (lane & 15)) * 64;
        bbase[i] = (ncol + i * 16 + (lane & 15)) * 64;
    }

    f32x4 acc[4][4];
#pragma unroll
    for (int i = 0; i < 4; i++)
#pragma unroll
        for (int j = 0; j < 4; j++) acc[i][j] = (f32x4){0.f, 0.f, 0.f, 0.f};

#define STG1(b)                                                                \
    do {                                                                       \
        _Pragma("unroll") for (int i_ = 0; i_ < 4; i_++) {                     \
            GLOAD_LDS16(gA[i_], &As[b][(i_ * 32 + w * 8) * 64]);               \
            GLOAD_LDS16(gB[i_], &Bs[b][(i_ * 32 + w * 8) * 64]);               \
            gA[i_] += 64; gB[i_] += 64;                                        \
        }                                                                      \
    } while (0)

    STG1(0);
    const int nk = K >> 6;
    for (int it = 0; it < nk; it++) {
        const int buf = it & 1;
        __syncthreads();
        if (it + 1 < nk) STG1(buf ^ 1);
#pragma unroll
        for (int s = 0; s < 2; s++) {
            bf16x8 af[4], bfr[4];
#pragma unroll
            for (int i = 0; i < 4; i++) {
                af[i] = *reinterpret_cast<const bf16x8*>(&As[buf][abase[i] + ph[s]]);
                bfr[i] = *reinterpret_cast<const bf16x8*>(&Bs[buf][bbase[i] + ph[s]]);
            }
#pragma unroll
            for (int i = 0; i < 4; i++)
#pragma unroll
                for (int j = 0; j < 4; j++)
                    acc[i][j] = __builtin_amdgcn_mfma_f32_16x16x32_bf16(
                        af[i], bfr[j], acc[i][j], 0, 0, 0);
        }
    }
#undef STG1

    const int ccol = lane & 15;
    const int crow = (lane >> 4) << 2;
#pragma unroll
    for (int i = 0; i < 4; i++) {
#pragma unroll
        for (int j = 0; j < 4; j++) {
            int col = n0 + ncol + j * 16 + ccol;
            float badd = bias[col];
#pragma unroll
            for (int r = 0; r < 4; r++) {
                int row = m0 + mrow + i * 16 + crow + r;
                C[(size_t)row * N + col] = f2bf(gelu_f(acc[i][j][r] + badd));
            }
        }
    }
}

// ---------------------------------------------------------------------------
// N=1024 GEMM, 64x64 tile, BK=64 double-buffered, XCD mapping (x = m-tile).
// Grid (M/64, N/64) = 64x16 = 1024 blocks.  (O-proj only.)
// EPI 1: C = acc + bias[n] + resid (fp32); resid prefetched pre-K-loop.
// ---------------------------------------------------------------------------
template <int EPI>
__global__ __launch_bounds__(256) void mfma_gemm_s64(
    const unsigned short* __restrict__ A,   // M x K bf16
    const unsigned short* __restrict__ Bt,  // N x K bf16
    float* __restrict__ C,
    const float* __restrict__ bias,
    const float* __restrict__ resid,
    int M, int N, int K) {
    __shared__ unsigned short As[2][64 * 64];  // 16 KB
    __shared__ unsigned short Bs[2][64 * 64];  // 16 KB

    const int t = threadIdx.x;
    const int w = t >> 6, lane = t & 63;
    const int m0 = blockIdx.x * 64, n0 = blockIdx.y * 64;

    const int srow = lane >> 3;
    const int sc = (lane & 7) ^ srow;
    const unsigned short* gA[2];
    const unsigned short* gB[2];
#pragma unroll
    for (int i = 0; i < 2; i++) {
        gA[i] = A + (size_t)(m0 + i * 32 + w * 8 + srow) * K + sc * 8;
        gB[i] = Bt + (size_t)(n0 + i * 32 + w * 8 + srow) * K + sc * 8;
    }

    int ph[2];
#pragma unroll
    for (int s = 0; s < 2; s++) ph[s] = ((s * 4 + (lane >> 4)) ^ (lane & 7)) * 8;
    // wave tile 32x32: rows mrow..mrow+31, cols ncol..ncol+31
    const int mrow = (w >> 1) * 32, ncol = (w & 1) * 32;
    int abase[2], bbase[2];
#pragma unroll
    for (int i = 0; i < 2; i++) {
        abase[i] = (mrow + i * 16 + (lane & 15)) * 64;
        bbase[i] = (ncol + i * 16 + (lane & 15)) * 64;
    }

    const int ccol = lane & 15;
    const int crow = (lane >> 4) << 2;

    // prefetch resid tile into registers (EPI 1 only): hides the HBM read
    float rpre[2][2][4];
    if constexpr (EPI == 1) {
#pragma unroll
        for (int i = 0; i < 2; i++)
#pragma unroll
            for (int j = 0; j < 2; j++)
#pragma unroll
                for (int r = 0; r < 4; r++) {
                    int row = m0 + mrow + i * 16 + crow + r;
                    int col = n0 + ncol + j * 16 + ccol;
                    rpre[i][j][r] = resid[(size_t)row * N + col];
                }
    }

    f32x4 acc[2][2];
#pragma unroll
    for (int i = 0; i < 2; i++)
#pragma unroll
        for (int j = 0; j < 2; j++) acc[i][j] = (f32x4){0.f, 0.f, 0.f, 0.f};

#define STGS(b)                                                                \
    do {                                                                       \
        _Pragma("unroll") for (int i_ = 0; i_ < 2; i_++) {                     \
            GLOAD_LDS16(gA[i_], &As[b][(i_ * 32 + w * 8) * 64]);               \
            GLOAD_LDS16(gB[i_], &Bs[b][(i_ * 32 + w * 8) * 64]);               \
            gA[i_] += 64; gB[i_] += 64;                                        \
        }                                                                      \
    } while (0)

    STGS(0);
    const int nk = K >> 6;
    for (int it = 0; it < nk; it++) {
        const int buf = it & 1;
        __syncthreads();
        if (it + 1 < nk) STGS(buf ^ 1);
#pragma unroll
        for (int s = 0; s < 2; s++) {
            bf16x8 af[2], bfr[2];
#pragma unroll
            for (int i = 0; i < 2; i++) {
                af[i] = *reinterpret_cast<const bf16x8*>(&As[buf][abase[i] + ph[s]]);
                bfr[i] = *reinterpret_cast<const bf16x8*>(&Bs[buf][bbase[i] + ph[s]]);
            }
#pragma unroll
            for (int i = 0; i < 2; i++)
#pragma unroll
                for (int j = 0; j < 2; j++)
                    acc[i][j] = __builtin_amdgcn_mfma_f32_16x16x32_bf16(
                        af[i], bfr[j], acc[i][j], 0, 0, 0);
        }
    }
#undef STGS

#pragma unroll
    for (int i = 0; i < 2; i++) {
#pragma unroll
        for (int j = 0; j < 2; j++) {
            int col = n0 + ncol + j * 16 + ccol;
            float badd = bias[col];
#pragma unroll
            for (int r = 0; r < 4; r++) {
                int row = m0 + mrow + i * 16 + crow + r;
                size_t idx = (size_t)row * N + col;
                if constexpr (EPI == 1) {
                    C[idx] = acc[i][j][r] + badd + rpre[i][j][r];
                } else {
                    C[idx] = C[idx] + acc[i][j][r] + badd;
                }
            }
        }
    }
}

// ---------------------------------------------------------------------------
// FF2 GEMM v8: r0 anchor geometry (64x64, BK=64 dbuf, 1024 blocks = 4/CU,
// RMW epilogue) + T4 counted-vmcnt depth-2 prefetch.
// The anchor's __syncthreads drains vmcnt(0) every K-step, exposing
// (HBM latency - one compute phase) per iteration.  Here: stage TWO tiles
// ahead; before reading tile it, wait vmcnt(4) (tile it+1's 4 loads stay
// in flight across the raw s_barrier).  Barrier B separates reads of buf
// from the depth-2 restage into buf.  Per-wave vmcnt + barrier A ==> all
// waves' tile-it loads complete before any wave reads (safe).
// ---------------------------------------------------------------------------
__global__ __launch_bounds__(256) void ff2_gemm(
    const unsigned short* __restrict__ A,   // M x K bf16
    const unsigned short* __restrict__ Bt,  // N x K bf16
    float* __restrict__ C,                  // fp32, RMW +=
    const float* __restrict__ bias,
    int M, int N, int K) {
    __shared__ unsigned short As[2][64 * 64];  // 16 KB
    __shared__ unsigned short Bs[2][64 * 64];  // 16 KB

    const int t = threadIdx.x;
    const int w = t >> 6, lane = t & 63;
    const int m0 = blockIdx.x * 64, n0 = blockIdx.y * 64;

    const int srow = lane >> 3;
    const int sc = (lane & 7) ^ srow;
    const unsigned short* gA[2];
    const unsigned short* gB[2];
#pragma unroll
    for (int i = 0; i < 2; i++) {
        gA[i] = A + (size_t)(m0 + i * 32 + w * 8 + srow) * K + sc * 8;
        gB[i] = Bt + (size_t)(n0 + i * 32 + w * 8 + srow) * K + sc * 8;
    }

    int ph[2];
#pragma unroll
    for (int s = 0; s < 2; s++) ph[s] = ((s * 4 + (lane >> 4)) ^ (lane & 7)) * 8;
    const int mrow = (w >> 1) * 32, ncol = (w & 1) * 32;
    int abase[2], bbase[2];
#pragma unroll
    for (int i = 0; i < 2; i++) {
        abase[i] = (mrow + i * 16 + (lane & 15)) * 64;
        bbase[i] = (ncol + i * 16 + (lane & 15)) * 64;
    }

    f32x4 acc[2][2];
#pragma unroll
    for (int i = 0; i < 2; i++)
#pragma unroll
        for (int j = 0; j < 2; j++) acc[i][j] = (f32x4){0.f, 0.f, 0.f, 0.f};

#define STGF(b)                                                                \
    do {                                                                       \
        _Pragma("unroll") for (int i_ = 0; i_ < 2; i_++) {                     \
            GLOAD_LDS16(gA[i_], &As[b][(i_ * 32 + w * 8) * 64]);               \
            GLOAD_LDS16(gB[i_], &Bs[b][(i_ * 32 + w * 8) * 64]);               \
            gA[i_] += 64; gB[i_] += 64;                                        \
        }                                                                      \
    } while (0)

    // depth-2 prologue: tiles 0 and 1 in flight (4 loads each per wave)
    STGF(0);
    STGF(1);
    const int nk = K >> 6;
    for (int it = 0; it < nk; it++) {
        const int buf = it & 1;
        // wait for tile it's 4 loads; keep tile it+1's 4 in flight
        if (it + 1 < nk) {
            asm volatile("s_waitcnt vmcnt(4)" ::: "memory");
        } else {
            asm volatile("s_waitcnt vmcnt(0)" ::: "memory");
        }
        __builtin_amdgcn_sched_barrier(0);
        __builtin_amdgcn_s_barrier();       // A: all waves' tile-it loads done
        __builtin_amdgcn_sched_barrier(0);
#pragma unroll
        for (int s = 0; s < 2; s++) {
            bf16x8 af[2], bfr[2];
#pragma unroll
            for (int i = 0; i < 2; i++) {
                af[i] = *reinterpret_cast<const bf16x8*>(&As[buf][abase[i] + ph[s]]);
                bfr[i] = *reinterpret_cast<const bf16x8*>(&Bs[buf][bbase[i] + ph[s]]);
            }
#pragma unroll
            for (int i = 0; i < 2; i++)
#pragma unroll
                for (int j = 0; j < 2; j++)
                    acc[i][j] = __builtin_amdgcn_mfma_f32_16x16x32_bf16(
                        af[i], bfr[j], acc[i][j], 0, 0, 0);
        }
        __builtin_amdgcn_sched_barrier(0);
        __builtin_amdgcn_s_barrier();       // B: all waves done reading buf
        __builtin_amdgcn_sched_barrier(0);
        if (it + 2 < nk) STGF(buf);         // restage buf for tile it+2
    }
#undef STGF

    const int ccol = lane & 15;
    const int crow = (lane >> 4) << 2;
#pragma unroll
    for (int i = 0; i < 2; i++) {
#pragma unroll
        for (int j = 0; j < 2; j++) {
            int col = n0 + ncol + j * 16 + ccol;
            float badd = bias[col];
#pragma unroll
            for (int r = 0; r < 4; r++) {
                int row = m0 + mrow + i * 16 + crow + r;
                size_t idx = (size_t)row * N + col;
                C[idx] = C[idx] + acc[i][j][r] + badd;
            }
        }
    }
}

// ---------------------------------------------------------------------------
// Fused QKV, BK=64 double-buffered (r0-proven): 768 blocks.
//   [0,512):  qk: m = (bid&31)*128 (same-m -> same XCD), n = (bid>>5)*128
//   [512,768): vT[1024][4096] = wvT @ lnO^T
// ---------------------------------------------------------------------------
__global__ __launch_bounds__(256) void qkv_gemm(
    const unsigned short* __restrict__ lnO,   // [4096][1024]
    const unsigned short* __restrict__ wqkT,  // [2048][1024]
    const unsigned short* __restrict__ wvT,   // [1024][1024]
    unsigned short* __restrict__ q,           // [4096][1024]
    unsigned short* __restrict__ kb,          // [4096][1024]
    unsigned short* __restrict__ vT) {        // [1024][4096]
    __shared__ unsigned short As[2][128 * 64];
    __shared__ unsigned short Bs[2][128 * 64];

    const int t = threadIdx.x;
    const int w = t >> 6, lane = t & 63;
    const int bid = blockIdx.x;
    const bool qk = bid < 512;

    const unsigned short *A, *Bt;
    int m0, n0, N;
    if (qk) {
        A = lnO; Bt = wqkT;
        m0 = (bid & 31) * 128; n0 = (bid >> 5) * 128; N = 2048;
    } else {
        int lb = bid - 512;
        A = wvT; Bt = lnO;
        m0 = (lb & 7) * 128; n0 = (lb >> 3) * 128; N = 4096;
    }
    const int K = 1024;

    const int srow = lane >> 3;
    const int sc = (lane & 7) ^ srow;
    const unsigned short* gA[4];
    const unsigned short* gB[4];
#pragma unroll
    for (int i = 0; i < 4; i++) {
        gA[i] = A + (size_t)(m0 + i * 32 + w * 8 + srow) * K + sc * 8;
        gB[i] = Bt + (size_t)(n0 + i * 32 + w * 8 + srow) * K + sc * 8;
    }

    const int mrow = (w >> 1) * 64, ncol = (w & 1) * 64;
    int ph[2];
#pragma unroll
    for (int s = 0; s < 2; s++) ph[s] = ((s * 4 + (lane >> 4)) ^ (lane & 7)) * 8;
    int abase[4], bbase[4];
#pragma unroll
    for (int i = 0; i < 4; i++) {
        abase[i] = (mrow + i * 16 + (lane & 15)) * 64;
        bbase[i] = (ncol + i * 16 + (lane & 15)) * 64;
    }

    f32x4 acc[4][4];
#pragma unroll
    for (int i = 0; i < 4; i++)
#pragma unroll
        for (int j = 0; j < 4; j++) acc[i][j] = (f32x4){0.f, 0.f, 0.f, 0.f};

#define STGQ(b)                                                                \
    do {                                                                       \
        _Pragma("unroll") for (int i_ = 0; i_ < 4; i_++) {                     \
            GLOAD_LDS16(gA[i_], &As[b][(i_ * 32 + w * 8) * 64]);               \
            GLOAD_LDS16(gB[i_], &Bs[b][(i_ * 32 + w * 8) * 64]);               \
            gA[i_] += 64; gB[i_] += 64;                                        \
        }                                                                      \
    } while (0)

    STGQ(0);
    const int nk = K >> 6;
    for (int it = 0; it < nk; it++) {
        const int buf = it & 1;
        __syncthreads();
        if (it + 1 < nk) STGQ(buf ^ 1);
#pragma unroll
        for (int s = 0; s < 2; s++) {
            bf16x8 af[4], bfr[4];
#pragma unroll
            for (int i = 0; i < 4; i++) {
                af[i] = *reinterpret_cast<const bf16x8*>(&As[buf][abase[i] + ph[s]]);
                bfr[i] = *reinterpret_cast<const bf16x8*>(&Bs[buf][bbase[i] + ph[s]]);
            }
#pragma unroll
            for (int i = 0; i < 4; i++)
#pragma unroll
                for (int j = 0; j < 4; j++)
                    acc[i][j] = __builtin_amdgcn_mfma_f32_16x16x32_bf16(
                        af[i], bfr[j], acc[i][j], 0, 0, 0);
        }
    }
#undef STGQ

    const int ccol = lane & 15;
    const int crow = (lane >> 4) << 2;
    unsigned short* dst;
    int nbase;
    if (qk) {
        dst = (n0 < 1024) ? q : kb;
        nbase = n0 & 1023;
    } else {
        dst = vT;
        nbase = n0;
    }
    const int ldc = qk ? 1024 : 4096;
#pragma unroll
    for (int i = 0; i < 4; i++) {
#pragma unroll
        for (int j = 0; j < 4; j++) {
            int col = nbase + ncol + j * 16 + ccol;
#pragma unroll
            for (int r = 0; r < 4; r++) {
                int row = m0 + mrow + i * 16 + crow + r;
                dst[(size_t)row * ldc + col] = f2bf(acc[i][j][r]);
            }
        }
    }
}

// ---------------------------------------------------------------------------
// MFMA causal flash attention v6+T5: swapped operands (lane owns one q-row),
// lsum lane-local, P via cvt_pk + b64 writes, PV swapped (packed O-stores),
// s_setprio(1) around both MFMA clusters (T5).
// Grid (bh=32, pair=16): same-bh blocks 32 apart -> same XCD L2 for K/V.
// ---------------------------------------------------------------------------
__global__ __launch_bounds__(256) void attn_mfma(
    const unsigned short* __restrict__ Q,   // [4096][1024]
    const unsigned short* __restrict__ K,   // [4096][1024]
    const unsigned short* __restrict__ Vt,  // [1024][4096]
    unsigned short* __restrict__ O) {       // [4096][1024]
    __shared__ unsigned short Ks[2][64 * 64];
    __shared__ unsigned short Vs[2][64 * 64];
    __shared__ unsigned short Ps[4][16 * 64];

    const int t = threadIdx.x;
    const int w = t >> 6, lane = t & 63;
    const int l15 = lane & 15, l4 = lane >> 4;
    const int bh = blockIdx.x;    // 0..31  (same-bh -> same XCD)
    const int b = bh >> 4, h = bh & 15;
    const int pair = blockIdx.y;  // 0..15

    const int sr = (w << 3) + (lane >> 3);   // 0..31
    const int sc = lane & 7;
    const int c = sc ^ (sr & 7);
    const unsigned short* kbase = K + ((size_t)(b * SEQ)) * EMB + h * HD;
    const unsigned short* vbase = Vt + ((size_t)(h * HD)) * (size_t)NTOK + (size_t)b * SEQ;
    unsigned short* Pw = &Ps[w][0];

#define STAGE(k0s, buf)                                                        \
    do {                                                                       \
        GLOAD_LDS16(kbase + (size_t)((k0s) + sr) * EMB + c * 8,                \
                    &Ks[buf][(w << 3) * 64]);                                  \
        GLOAD_LDS16(kbase + (size_t)((k0s) + sr + 32) * EMB + c * 8,           \
                    &Ks[buf][((w << 3) + 32) * 64]);                           \
        GLOAD_LDS16(vbase + (size_t)sr * NTOK + (k0s) + c * 8,                 \
                    &Vs[buf][(w << 3) * 64]);                                  \
        GLOAD_LDS16(vbase + (size_t)(sr + 32) * NTOK + (k0s) + c * 8,          \
                    &Vs[buf][((w << 3) + 32) * 64]);                           \
    } while (0)

    const float C1 = 0.125f * 1.4426950408889634f;  // 1/sqrt(64) * log2e
    const float C2 = 3.0f * 1.4426950408889634f;    // fixed max = 3

#pragma unroll
    for (int phase = 0; phase < 2; phase++) {
        const int qt = phase ? pair : (31 - pair);
        const int q0 = qt * 64;

        const unsigned short* qg =
            Q + ((size_t)(b * SEQ + q0 + w * 16 + l15)) * EMB + h * HD + l4 * 8;
        bf16x8 qf0 = *(const bf16x8*)qg;
        bf16x8 qf1 = *(const bf16x8*)(qg + 32);
        const int qrow = q0 + w * 16 + l15;   // this lane's single q-row

        float ls[4] = {0.f, 0.f, 0.f, 0.f};
        f32x4 Oacc[4];
#pragma unroll
        for (int j = 0; j < 4; j++) Oacc[j] = (f32x4){0.f, 0.f, 0.f, 0.f};

        const int ntiles = qt + 1;
        __syncthreads();
        STAGE(0, 0);
        for (int tile = 0; tile < ntiles; tile++) {
            const int k0 = tile * 64;
            const int buf = tile & 1;
            __syncthreads();
            if (tile + 1 < ntiles) STAGE(k0 + 64, buf ^ 1);

            // S^T[k][q]: lane holds q = qrow, k = k0 + 16j + 4*l4 + r
            f32x4 S[4];
#pragma unroll
            for (int j = 0; j < 4; j++) S[j] = (f32x4){0.f, 0.f, 0.f, 0.f};
            __builtin_amdgcn_s_setprio(1);
#pragma unroll
            for (int s = 0; s < 2; s++) {
                bf16x8 qf = s ? qf1 : qf0;
#pragma unroll
                for (int j = 0; j < 4; j++) {
                    int rk = 16 * j + l15;
                    int phys = (s * 4 + l4) ^ (rk & 7);
                    bf16x8 kf = *(const bf16x8*)&Ks[buf][rk * 64 + phys * 8];
                    S[j] = __builtin_amdgcn_mfma_f32_16x16x32_bf16(kf, qf, S[j], 0, 0, 0);
                }
            }
            __builtin_amdgcn_s_setprio(0);

            if (tile == ntiles - 1) {
#pragma unroll
                for (int j = 0; j < 4; j++)
#pragma unroll
                    for (int r = 0; r < 4; r++) {
                        float e = exp2f(S[j][r] * C1 - C2);
                        if (k0 + 16 * j + 4 * l4 + r > qrow) e = 0.f;
                        S[j][r] = e;
                    }
            } else {
#pragma unroll
                for (int j = 0; j < 4; j++)
#pragma unroll
                    for (int r = 0; r < 4; r++)
                        S[j][r] = exp2f(S[j][r] * C1 - C2);
            }

            // pack P[q][k] into LDS: b64 per j (k = 16j+4*l4 .. +3),
            // chunk-XOR swizzle by (q&7) -> conflict-light write & b128 read
#pragma unroll
            for (int j = 0; j < 4; j++) {
                ls[j] += S[j][0] + S[j][1] + S[j][2] + S[j][3];
                unsigned int lo = cvt_pk_bf16(S[j][0], S[j][1]);
                unsigned int hi = cvt_pk_bf16(S[j][2], S[j][3]);
                int chunk = (2 * j + (l4 >> 1)) ^ (l15 & 7);
                uint2 val; val.x = lo; val.y = hi;
                *reinterpret_cast<uint2*>(&Pw[l15 * 64 + chunk * 8 + (l4 & 1) * 4]) = val;
            }

            // O^T = V^T * P^T: lane holds q = qrow, d = 16j + 4*l4 + r
            __builtin_amdgcn_s_setprio(1);
#pragma unroll
            for (int s = 0; s < 2; s++) {
                int pch = (4 * s + l4) ^ (l15 & 7);
                bf16x8 pf = *(const bf16x8*)&Pw[l15 * 64 + pch * 8];
#pragma unroll
                for (int j = 0; j < 4; j++) {
                    int rv = 16 * j + l15;
                    int vph = (s * 4 + l4) ^ (rv & 7);
                    bf16x8 vf = *(const bf16x8*)&Vs[buf][rv * 64 + vph * 8];
                    Oacc[j] = __builtin_amdgcn_mfma_f32_16x16x32_bf16(vf, pf, Oacc[j], 0, 0, 0);
                }
            }
            __builtin_amdgcn_s_setprio(0);
        }

        float l = ls[0] + ls[1] + ls[2] + ls[3];
        l += __shfl_xor(l, 16, 64);
        l += __shfl_xor(l, 32, 64);
        float inv = 1.f / l;
        size_t rowb = (size_t)(b * SEQ + qrow) * EMB + h * HD;
#pragma unroll
        for (int j = 0; j < 4; j++) {
            unsigned int lo = cvt_pk_bf16(Oacc[j][0] * inv, Oacc[j][1] * inv);
            unsigned int hi = cvt_pk_bf16(Oacc[j][2] * inv, Oacc[j][3] * inv);
            uint2 val; val.x = lo; val.y = hi;
            *reinterpret_cast<uint2*>(&O[rowb + 16 * j + 4 * l4]) = val;
        }
    }
#undef STAGE
}

// ---------------------------------------------------------------------------
// launch
// ---------------------------------------------------------------------------
extern "C" void kernel_launch(void* const* d_in, const int* in_sizes, int n_in,
                              void* d_out, int out_size, void* d_ws, size_t ws_size,
                              hipStream_t stream) {
    const float* x     = (const float*)d_in[0];
    const float* w_q   = (const float*)d_in[1];
    const float* w_k   = (const float*)d_in[2];
    const float* w_v   = (const float*)d_in[3];
    const float* w_o   = (const float*)d_in[4];
    const float* b_o   = (const float*)d_in[5];
    const float* ln1s  = (const float*)d_in[6];
    const float* ln1b  = (const float*)d_in[7];
    const float* ln2s  = (const float*)d_in[8];
    const float* ln2b  = (const float*)d_in[9];
    const float* w_ff1 = (const float*)d_in[10];
    const float* b_ff1 = (const float*)d_in[11];
    const float* w_ff2 = (const float*)d_in[12];
    const float* b_ff2 = (const float*)d_in[13];
    float* out = (float*)d_out;

    char* p = (char*)d_ws;
    unsigned short* lnO  = (unsigned short*)p; p += (size_t)NTOK * EMB * 2;      // 8 MB
    unsigned short* q    = (unsigned short*)p; p += (size_t)NTOK * EMB * 2;
    unsigned short* kbuf = (unsigned short*)p; p += (size_t)NTOK * EMB * 2;
    unsigned short* vT   = (unsigned short*)p; p += (size_t)NTOK * EMB * 2;
    unsigned short* ctx  = (unsigned short*)p; p += (size_t)NTOK * EMB * 2;      // attn out, later LN2 out
    unsigned short* ff1a = (unsigned short*)p; p += (size_t)NTOK * FF_DIM * 2;   // 32 MB
    unsigned short* wqkT = (unsigned short*)p; p += (size_t)2 * EMB * EMB * 2;   // 4 MB
    unsigned short* wvT  = (unsigned short*)p; p += (size_t)EMB * EMB * 2;
    unsigned short* woT  = (unsigned short*)p; p += (size_t)EMB * EMB * 2;
    unsigned short* wf1T = (unsigned short*)p; p += (size_t)FF_DIM * EMB * 2;    // 8 MB
    unsigned short* wf2T = (unsigned short*)p; p += (size_t)EMB * FF_DIM * 2;    // 8 MB

    dim3 blk(256);
    dim3 gS64(NTOK / 64, EMB / 64);         // 64 m x 16 n = 1024 blocks = 4/CU
    dim3 gFF1(NTOK / 128, FF_DIM / 128);    // 32 m x 32 n = 1024
    dim3 gAttn(BATCH * HEADS, 16);          // bh x pair; same-bh -> same XCD

    // fused weight transpose+cast + LN1
    prep_kernel<<<3072 + NTOK, blk, 0, stream>>>(
        w_q, w_k, w_v, w_o, w_ff1, w_ff2,
        wqkT, wqkT + (size_t)EMB * EMB, wvT, woT, wf1T, wf2T,
        x, ln1s, ln1b, lnO);
    qkv_gemm<<<768, blk, 0, stream>>>(lnO, wqkT, wvT, q, kbuf, vT);
    attn_mfma<<<gAttn, blk, 0, stream>>>(q, kbuf, vT, ctx);
    // O-proj fused: out = x + b_o + ctx @ w_o   (64x64 tiles, 1024 blocks)
    mfma_gemm_s64<1><<<gS64, blk, 0, stream>>>(ctx, woT, out, b_o, x, NTOK, EMB, EMB);
    // LN2: out -> ctx (bf16)
    ln_kernel<<<NTOK, blk, 0, stream>>>(out, ln2s, ln2b, ctx);
    // FF1 + cheap gelu epilogue
    ff1_gemm<<<gFF1, blk, 0, stream>>>(ctx, wf1T, ff1a, b_ff1, NTOK, FF_DIM, EMB);
    // FF2 anchor + counted-vmcnt depth-2: out += ff1a @ w_ff2 + b_ff2
    ff2_gemm<<<gS64, blk, 0, stream>>>(ff1a, wf2T, out, b_ff2, NTOK, EMB, FF_DIM);
}

// Round 9
// 318.691 us; speedup vs baseline: 1.0681x; 1.0021x over previous
//
#include <hip/hip_runtime.h>
#include <math.h>

#define EMB 1024
#define HEADS 16
#define HD 64
#define FF_DIM 4096
#define SEQ 2048
#define BATCH 2
#define NTOK (BATCH * SEQ)   // 4096

typedef __bf16 bf16x8 __attribute__((ext_vector_type(8)));
typedef float f32x4 __attribute__((ext_vector_type(4)));

__device__ __forceinline__ unsigned short f2bf(float f) {
    union { float f; unsigned int u; } v; v.f = f;
    unsigned int r = v.u + 0x7fff + ((v.u >> 16) & 1);  // RNE
    return (unsigned short)(r >> 16);
}

// pack 2 fp32 -> 2 bf16 in one u32 (no builtin on gfx950; inline asm)
__device__ __forceinline__ unsigned int cvt_pk_bf16(float a, float b) {
    unsigned int r;
    asm("v_cvt_pk_bf16_f32 %0, %1, %2" : "=v"(r) : "v"(a), "v"(b));
    return r;
}

// gelu_tanh(x) = 0.5x(1+tanh(z)) = x*sigmoid(2z), z = c(x+0.044715x^3).
__device__ __forceinline__ float gelu_f(float x) {
    const float A = 1.5957691216057308f;   // 2c, c = sqrt(2/pi)
    const float B = 0.07135481282989427f;  // 2c*0.044715
    float zz = x * (A + B * x * x);
    return x * __builtin_amdgcn_rcpf(1.f + __expf(-zz));
}

#define GLOAD_LDS16(g, l)                                                      \
    __builtin_amdgcn_global_load_lds(                                          \
        (const __attribute__((address_space(1))) void*)(g),                    \
        (__attribute__((address_space(3))) void*)(l), 16, 0, 0)

// ---------------------------------------------------------------------------
// LayerNorm: one block per row of 1024, fp32 in -> bf16 out.
// float4 loads (16B/lane), ushort4 packed stores (G13).
// ---------------------------------------------------------------------------
__global__ __launch_bounds__(256) void ln_kernel(const float* __restrict__ x,
                                                 const float* __restrict__ scale,
                                                 const float* __restrict__ shift,
                                                 unsigned short* __restrict__ out) {
    int row = blockIdx.x;
    const float4* xr = (const float4*)(x + (size_t)row * EMB);
    int t = threadIdx.x;

    float4 v = xr[t];
    float s = v.x + v.y + v.z + v.w;
    float s2 = v.x * v.x + v.y * v.y + v.z * v.z + v.w * v.w;
    for (int o = 32; o > 0; o >>= 1) {
        s += __shfl_down(s, o, 64);
        s2 += __shfl_down(s2, o, 64);
    }
    __shared__ float red[4], red2[4];
    int wave = t >> 6;
    if ((t & 63) == 0) { red[wave] = s; red2[wave] = s2; }
    __syncthreads();
    if (t == 0) {
        float a = 0.f, b = 0.f;
#pragma unroll
        for (int i = 0; i < 4; i++) { a += red[i]; b += red2[i]; }
        red[0] = a; red2[0] = b;
    }
    __syncthreads();
    float mean = red[0] * (1.f / EMB);
    float var = red2[0] * (1.f / EMB) - mean * mean;
    float rstd = rsqrtf(var + 1e-5f);

    float4 sc = ((const float4*)scale)[t];
    float4 sh = ((const float4*)shift)[t];
    ushort4 o;
    o.x = f2bf(sc.x * (v.x - mean) * rstd + sh.x);
    o.y = f2bf(sc.y * (v.y - mean) * rstd + sh.y);
    o.z = f2bf(sc.z * (v.z - mean) * rstd + sh.z);
    o.w = f2bf(sc.w * (v.w - mean) * rstd + sh.w);
    ((ushort4*)(out + (size_t)row * EMB))[t] = o;
}

// ---------------------------------------------------------------------------
// Prep v9: blocks [0,768) = transpose+cast wq/wk/wv ONLY (the weights qkv
// needs immediately).  woT/wf1T/wf2T moved into the attn launch (they are
// not consumed until after attention -> their 48 MB of traffic rides free
// in attn's idle CU slots).  Blocks [768, 768+4096) = LN1 rows.
// ---------------------------------------------------------------------------
__global__ __launch_bounds__(256) void prep_kernel(
    const float* __restrict__ w0, const float* __restrict__ w1,
    const float* __restrict__ w2,
    unsigned short* __restrict__ o0, unsigned short* __restrict__ o1,
    unsigned short* __restrict__ o2,
    const float* __restrict__ x, const float* __restrict__ ln1s,
    const float* __restrict__ ln1b, unsigned short* __restrict__ lnO) {
    __shared__ float tile[64][65];
    __shared__ float red[4], red2[4];
    int id = blockIdx.x;
    int t = threadIdx.x;

    if (id >= 768) {
        // ---- LN1 path ----
        int row = id - 768;
        const float4* xr = (const float4*)(x + (size_t)row * EMB);
        float4 v = xr[t];
        float s = v.x + v.y + v.z + v.w;
        float s2 = v.x * v.x + v.y * v.y + v.z * v.z + v.w * v.w;
        for (int o = 32; o > 0; o >>= 1) {
            s += __shfl_down(s, o, 64);
            s2 += __shfl_down(s2, o, 64);
        }
        int wave = t >> 6;
        if ((t & 63) == 0) { red[wave] = s; red2[wave] = s2; }
        __syncthreads();
        if (t == 0) {
            float a = 0.f, b = 0.f;
#pragma unroll
            for (int i = 0; i < 4; i++) { a += red[i]; b += red2[i]; }
            red[0] = a; red2[0] = b;
        }
        __syncthreads();
        float mean = red[0] * (1.f / EMB);
        float var = red2[0] * (1.f / EMB) - mean * mean;
        float rstd = rsqrtf(var + 1e-5f);

        float4 sc = ((const float4*)ln1s)[t];
        float4 sh = ((const float4*)ln1b)[t];
        ushort4 o;
        o.x = f2bf(sc.x * (v.x - mean) * rstd + sh.x);
        o.y = f2bf(sc.y * (v.y - mean) * rstd + sh.y);
        o.z = f2bf(sc.z * (v.z - mean) * rstd + sh.z);
        o.w = f2bf(sc.w * (v.w - mean) * rstd + sh.w);
        ((ushort4*)(lnO + (size_t)row * EMB))[t] = o;
        return;
    }

    // ---- transpose+cast path (wq/wk/wv: K=N=1024, 256 blocks each) ----
    const float* src; unsigned short* dst; int lid;
    if (id < 256)       { src = w0; dst = o0; lid = id; }
    else if (id < 512)  { src = w1; dst = o1; lid = id - 256; }
    else                { src = w2; dst = o2; lid = id - 512; }
    const int K = 1024, N = 1024;
    int tn = N >> 6;
    int k0 = (lid / tn) << 6, n0 = (lid % tn) << 6;
    int rr = t >> 6, cc = t & 63;
#pragma unroll
    for (int i = 0; i < 16; i++) {
        int r = i * 4 + rr;
        tile[r][cc] = src[(size_t)(k0 + r) * N + n0 + cc];
    }
    __syncthreads();
#pragma unroll
    for (int i = 0; i < 16; i++) {
        int r = i * 4 + rr;
        dst[(size_t)(n0 + r) * K + k0 + cc] = f2bf(tile[cc][r]);
    }
}

// ===========================================================================
// BK=64 staging geometry: LDS row = 64 elems (128 B) = 8 x 16B chunks.
// Physical chunk p of row r holds logical chunk p ^ (r & 7); fragment
// ds_read_b128 aliases 2-way (free). Per global_load_lds instr: 8 rows;
// lane l -> row base+(l>>3), logical chunk (l&7)^(l>>3).
//
// FF2 invariants (r1-r8): {64^2 tile, BK=64 dbuf, 1024-block 2D x=m grid,
// FULL 4/CU co-residency, RMW epilogue} + counted-vmcnt depth-2 (r8, +1%).
// r8 verdict: FF2 is at this structure's floor.  r9 extends the verified
// counted-vmcnt pattern to ff1/qkv (2 blocks/CU -> drain less well hidden).
// ===========================================================================

// ---------------------------------------------------------------------------
// FF1 GEMM, 128x128 tile, BK=64 dbuf + counted-vmcnt depth-2 (r8 pattern).
// Epilogue: bf16 gelu(acc + bias[n]).
// ---------------------------------------------------------------------------
__global__ __launch_bounds__(256) void ff1_gemm(
    const unsigned short* __restrict__ A,   // M x K bf16
    const unsigned short* __restrict__ Bt,  // N x K bf16
    unsigned short* __restrict__ C,
    const float* __restrict__ bias,
    int M, int N, int K) {
    __shared__ unsigned short As[2][128 * 64];  // 32 KB
    __shared__ unsigned short Bs[2][128 * 64];  // 32 KB

    const int t = threadIdx.x;
    const int w = t >> 6, lane = t & 63;
    const int m0 = blockIdx.x * 128, n0 = blockIdx.y * 128;

    const int srow = lane >> 3;
    const int sc = (lane & 7) ^ srow;   // logical chunk (elems*8)
    const unsigned short* gA[4];
    const unsigned short* gB[4];
#pragma unroll
    for (int i = 0; i < 4; i++) {
        gA[i] = A + (size_t)(m0 + i * 32 + w * 8 + srow) * K + sc * 8;
        gB[i] = Bt + (size_t)(n0 + i * 32 + w * 8 + srow) * K + sc * 8;
    }

    const int mrow = (w >> 1) * 64, ncol = (w & 1) * 64;
    int ph[2];
#pragma unroll
    for (int s = 0; s < 2; s++) ph[s] = ((s * 4 + (lane >> 4)) ^ (lane & 7)) * 8;
    int abase[4], bbase[4];
#pragma unroll
    for (int i = 0; i < 4; i++) {
        abase[i] = (mrow + i * 16 + (lane & 15)) * 64;
        bbase[i] = (ncol + i * 16 + (lane & 15)) * 64;
    }

    f32x4 acc[4][4];
#pragma unroll
    for (int i = 0; i < 4; i++)
#pragma unroll
        for (int j = 0; j < 4; j++) acc[i][j] = (f32x4){0.f, 0.f, 0.f, 0.f};

#define STG1(b)                                                                \
    do {                                                                       \
        _Pragma("unroll") for (int i_ = 0; i_ < 4; i_++) {                     \
            GLOAD_LDS16(gA[i_], &As[b][(i_ * 32 + w * 8) * 64]);               \
            GLOAD_LDS16(gB[i_], &Bs[b][(i_ * 32 + w * 8) * 64]);               \
            gA[i_] += 64; gB[i_] += 64;                                        \
        }                                                                      \
    } while (0)

    // depth-2 prologue: tiles 0 and 1 in flight (8 loads each per wave)
    STG1(0);
    STG1(1);
    const int nk = K >> 6;
    for (int it = 0; it < nk; it++) {
        const int buf = it & 1;
        if (it + 1 < nk) {
            asm volatile("s_waitcnt vmcnt(8)" ::: "memory");
        } else {
            asm volatile("s_waitcnt vmcnt(0)" ::: "memory");
        }
        __builtin_amdgcn_sched_barrier(0);
        __builtin_amdgcn_s_barrier();       // A: tile-it loads visible
        __builtin_amdgcn_sched_barrier(0);
#pragma unroll
        for (int s = 0; s < 2; s++) {
            bf16x8 af[4], bfr[4];
#pragma unroll
            for (int i = 0; i < 4; i++) {
                af[i] = *reinterpret_cast<const bf16x8*>(&As[buf][abase[i] + ph[s]]);
                bfr[i] = *reinterpret_cast<const bf16x8*>(&Bs[buf][bbase[i] + ph[s]]);
            }
#pragma unroll
            for (int i = 0; i < 4; i++)
#pragma unroll
                for (int j = 0; j < 4; j++)
                    acc[i][j] = __builtin_amdgcn_mfma_f32_16x16x32_bf16(
                        af[i], bfr[j], acc[i][j], 0, 0, 0);
        }
        __builtin_amdgcn_sched_barrier(0);
        __builtin_amdgcn_s_barrier();       // B: all waves done reading buf
        __builtin_amdgcn_sched_barrier(0);
        if (it + 2 < nk) STG1(buf);         // restage buf for tile it+2
    }
#undef STG1

    const int ccol = lane & 15;
    const int crow = (lane >> 4) << 2;
#pragma unroll
    for (int i = 0; i < 4; i++) {
#pragma unroll
        for (int j = 0; j < 4; j++) {
            int col = n0 + ncol + j * 16 + ccol;
            float badd = bias[col];
#pragma unroll
            for (int r = 0; r < 4; r++) {
                int row = m0 + mrow + i * 16 + crow + r;
                C[(size_t)row * N + col] = f2bf(gelu_f(acc[i][j][r] + badd));
            }
        }
    }
}

// ---------------------------------------------------------------------------
// N=1024 GEMM, 64x64 tile, BK=64 double-buffered, XCD mapping (x = m-tile).
// Grid (M/64, N/64) = 64x16 = 1024 blocks.  (O-proj only.)
// EPI 1: C = acc + bias[n] + resid (fp32); resid prefetched pre-K-loop.
// ---------------------------------------------------------------------------
template <int EPI>
__global__ __launch_bounds__(256) void mfma_gemm_s64(
    const unsigned short* __restrict__ A,   // M x K bf16
    const unsigned short* __restrict__ Bt,  // N x K bf16
    float* __restrict__ C,
    const float* __restrict__ bias,
    const float* __restrict__ resid,
    int M, int N, int K) {
    __shared__ unsigned short As[2][64 * 64];  // 16 KB
    __shared__ unsigned short Bs[2][64 * 64];  // 16 KB

    const int t = threadIdx.x;
    const int w = t >> 6, lane = t & 63;
    const int m0 = blockIdx.x * 64, n0 = blockIdx.y * 64;

    const int srow = lane >> 3;
    const int sc = (lane & 7) ^ srow;
    const unsigned short* gA[2];
    const unsigned short* gB[2];
#pragma unroll
    for (int i = 0; i < 2; i++) {
        gA[i] = A + (size_t)(m0 + i * 32 + w * 8 + srow) * K + sc * 8;
        gB[i] = Bt + (size_t)(n0 + i * 32 + w * 8 + srow) * K + sc * 8;
    }

    int ph[2];
#pragma unroll
    for (int s = 0; s < 2; s++) ph[s] = ((s * 4 + (lane >> 4)) ^ (lane & 7)) * 8;
    // wave tile 32x32: rows mrow..mrow+31, cols ncol..ncol+31
    const int mrow = (w >> 1) * 32, ncol = (w & 1) * 32;
    int abase[2], bbase[2];
#pragma unroll
    for (int i = 0; i < 2; i++) {
        abase[i] = (mrow + i * 16 + (lane & 15)) * 64;
        bbase[i] = (ncol + i * 16 + (lane & 15)) * 64;
    }

    const int ccol = lane & 15;
    const int crow = (lane >> 4) << 2;

    // prefetch resid tile into registers (EPI 1 only): hides the HBM read
    float rpre[2][2][4];
    if constexpr (EPI == 1) {
#pragma unroll
        for (int i = 0; i < 2; i++)
#pragma unroll
            for (int j = 0; j < 2; j++)
#pragma unroll
                for (int r = 0; r < 4; r++) {
                    int row = m0 + mrow + i * 16 + crow + r;
                    int col = n0 + ncol + j * 16 + ccol;
                    rpre[i][j][r] = resid[(size_t)row * N + col];
                }
    }

    f32x4 acc[2][2];
#pragma unroll
    for (int i = 0; i < 2; i++)
#pragma unroll
        for (int j = 0; j < 2; j++) acc[i][j] = (f32x4){0.f, 0.f, 0.f, 0.f};

#define STGS(b)                                                                \
    do {                                                                       \
        _Pragma("unroll") for (int i_ = 0; i_ < 2; i_++) {                     \
            GLOAD_LDS16(gA[i_], &As[b][(i_ * 32 + w * 8) * 64]);               \
            GLOAD_LDS16(gB[i_], &Bs[b][(i_ * 32 + w * 8) * 64]);               \
            gA[i_] += 64; gB[i_] += 64;                                        \
        }                                                                      \
    } while (0)

    STGS(0);
    const int nk = K >> 6;
    for (int it = 0; it < nk; it++) {
        const int buf = it & 1;
        __syncthreads();
        if (it + 1 < nk) STGS(buf ^ 1);
#pragma unroll
        for (int s = 0; s < 2; s++) {
            bf16x8 af[2], bfr[2];
#pragma unroll
            for (int i = 0; i < 2; i++) {
                af[i] = *reinterpret_cast<const bf16x8*>(&As[buf][abase[i] + ph[s]]);
                bfr[i] = *reinterpret_cast<const bf16x8*>(&Bs[buf][bbase[i] + ph[s]]);
            }
#pragma unroll
            for (int i = 0; i < 2; i++)
#pragma unroll
                for (int j = 0; j < 2; j++)
                    acc[i][j] = __builtin_amdgcn_mfma_f32_16x16x32_bf16(
                        af[i], bfr[j], acc[i][j], 0, 0, 0);
        }
    }
#undef STGS

#pragma unroll
    for (int i = 0; i < 2; i++) {
#pragma unroll
        for (int j = 0; j < 2; j++) {
            int col = n0 + ncol + j * 16 + ccol;
            float badd = bias[col];
#pragma unroll
            for (int r = 0; r < 4; r++) {
                int row = m0 + mrow + i * 16 + crow + r;
                size_t idx = (size_t)row * N + col;
                if constexpr (EPI == 1) {
                    C[idx] = acc[i][j][r] + badd + rpre[i][j][r];
                } else {
                    C[idx] = C[idx] + acc[i][j][r] + badd;
                }
            }
        }
    }
}

// ---------------------------------------------------------------------------
// FF2 GEMM (r8-verified): 64x64 anchor + counted-vmcnt depth-2.
// ---------------------------------------------------------------------------
__global__ __launch_bounds__(256) void ff2_gemm(
    const unsigned short* __restrict__ A,   // M x K bf16
    const unsigned short* __restrict__ Bt,  // N x K bf16
    float* __restrict__ C,                  // fp32, RMW +=
    const float* __restrict__ bias,
    int M, int N, int K) {
    __shared__ unsigned short As[2][64 * 64];  // 16 KB
    __shared__ unsigned short Bs[2][64 * 64];  // 16 KB

    const int t = threadIdx.x;
    const int w = t >> 6, lane = t & 63;
    const int m0 = blockIdx.x * 64, n0 = blockIdx.y * 64;

    const int srow = lane >> 3;
    const int sc = (lane & 7) ^ srow;
    const unsigned short* gA[2];
    const unsigned short* gB[2];
#pragma unroll
    for (int i = 0; i < 2; i++) {
        gA[i] = A + (size_t)(m0 + i * 32 + w * 8 + srow) * K + sc * 8;
        gB[i] = Bt + (size_t)(n0 + i * 32 + w * 8 + srow) * K + sc * 8;
    }

    int ph[2];
#pragma unroll
    for (int s = 0; s < 2; s++) ph[s] = ((s * 4 + (lane >> 4)) ^ (lane & 7)) * 8;
    const int mrow = (w >> 1) * 32, ncol = (w & 1) * 32;
    int abase[2], bbase[2];
#pragma unroll
    for (int i = 0; i < 2; i++) {
        abase[i] = (mrow + i * 16 + (lane & 15)) * 64;
        bbase[i] = (ncol + i * 16 + (lane & 15)) * 64;
    }

    f32x4 acc[2][2];
#pragma unroll
    for (int i = 0; i < 2; i++)
#pragma unroll
        for (int j = 0; j < 2; j++) acc[i][j] = (f32x4){0.f, 0.f, 0.f, 0.f};

#define STGF(b)                                                                \
    do {                                                                       \
        _Pragma("unroll") for (int i_ = 0; i_ < 2; i_++) {                     \
            GLOAD_LDS16(gA[i_], &As[b][(i_ * 32 + w * 8) * 64]);               \
            GLOAD_LDS16(gB[i_], &Bs[b][(i_ * 32 + w * 8) * 64]);               \
            gA[i_] += 64; gB[i_] += 64;                                        \
        }                                                                      \
    } while (0)

    STGF(0);
    STGF(1);
    const int nk = K >> 6;
    for (int it = 0; it < nk; it++) {
        const int buf = it & 1;
        if (it + 1 < nk) {
            asm volatile("s_waitcnt vmcnt(4)" ::: "memory");
        } else {
            asm volatile("s_waitcnt vmcnt(0)" ::: "memory");
        }
        __builtin_amdgcn_sched_barrier(0);
        __builtin_amdgcn_s_barrier();       // A: all waves' tile-it loads done
        __builtin_amdgcn_sched_barrier(0);
#pragma unroll
        for (int s = 0; s < 2; s++) {
            bf16x8 af[2], bfr[2];
#pragma unroll
            for (int i = 0; i < 2; i++) {
                af[i] = *reinterpret_cast<const bf16x8*>(&As[buf][abase[i] + ph[s]]);
                bfr[i] = *reinterpret_cast<const bf16x8*>(&Bs[buf][bbase[i] + ph[s]]);
            }
#pragma unroll
            for (int i = 0; i < 2; i++)
#pragma unroll
                for (int j = 0; j < 2; j++)
                    acc[i][j] = __builtin_amdgcn_mfma_f32_16x16x32_bf16(
                        af[i], bfr[j], acc[i][j], 0, 0, 0);
        }
        __builtin_amdgcn_sched_barrier(0);
        __builtin_amdgcn_s_barrier();       // B: all waves done reading buf
        __builtin_amdgcn_sched_barrier(0);
        if (it + 2 < nk) STGF(buf);         // restage buf for tile it+2
    }
#undef STGF

    const int ccol = lane & 15;
    const int crow = (lane >> 4) << 2;
#pragma unroll
    for (int i = 0; i < 2; i++) {
#pragma unroll
        for (int j = 0; j < 2; j++) {
            int col = n0 + ncol + j * 16 + ccol;
            float badd = bias[col];
#pragma unroll
            for (int r = 0; r < 4; r++) {
                int row = m0 + mrow + i * 16 + crow + r;
                size_t idx = (size_t)row * N + col;
                C[idx] = C[idx] + acc[i][j][r] + badd;
            }
        }
    }
}

// ---------------------------------------------------------------------------
// Fused QKV, BK=64 dbuf + counted-vmcnt depth-2 (r8 pattern): 768 blocks.
//   [0,512):  qk: m = (bid&31)*128 (same-m -> same XCD), n = (bid>>5)*128
//   [512,768): vT[1024][4096] = wvT @ lnO^T
// ---------------------------------------------------------------------------
__global__ __launch_bounds__(256) void qkv_gemm(
    const unsigned short* __restrict__ lnO,   // [4096][1024]
    const unsigned short* __restrict__ wqkT,  // [2048][1024]
    const unsigned short* __restrict__ wvT,   // [1024][1024]
    unsigned short* __restrict__ q,           // [4096][1024]
    unsigned short* __restrict__ kb,          // [4096][1024]
    unsigned short* __restrict__ vT) {        // [1024][4096]
    __shared__ unsigned short As[2][128 * 64];
    __shared__ unsigned short Bs[2][128 * 64];

    const int t = threadIdx.x;
    const int w = t >> 6, lane = t & 63;
    const int bid = blockIdx.x;
    const bool qk = bid < 512;

    const unsigned short *A, *Bt;
    int m0, n0, N;
    if (qk) {
        A = lnO; Bt = wqkT;
        m0 = (bid & 31) * 128; n0 = (bid >> 5) * 128; N = 2048;
    } else {
        int lb = bid - 512;
        A = wvT; Bt = lnO;
        m0 = (lb & 7) * 128; n0 = (lb >> 3) * 128; N = 4096;
    }
    const int K = 1024;

    const int srow = lane >> 3;
    const int sc = (lane & 7) ^ srow;
    const unsigned short* gA[4];
    const unsigned short* gB[4];
#pragma unroll
    for (int i = 0; i < 4; i++) {
        gA[i] = A + (size_t)(m0 + i * 32 + w * 8 + srow) * K + sc * 8;
        gB[i] = Bt + (size_t)(n0 + i * 32 + w * 8 + srow) * K + sc * 8;
    }

    const int mrow = (w >> 1) * 64, ncol = (w & 1) * 64;
    int ph[2];
#pragma unroll
    for (int s = 0; s < 2; s++) ph[s] = ((s * 4 + (lane >> 4)) ^ (lane & 7)) * 8;
    int abase[4], bbase[4];
#pragma unroll
    for (int i = 0; i < 4; i++) {
        abase[i] = (mrow + i * 16 + (lane & 15)) * 64;
        bbase[i] = (ncol + i * 16 + (lane & 15)) * 64;
    }

    f32x4 acc[4][4];
#pragma unroll
    for (int i = 0; i < 4; i++)
#pragma unroll
        for (int j = 0; j < 4; j++) acc[i][j] = (f32x4){0.f, 0.f, 0.f, 0.f};

#define STGQ(b)                                                                \
    do {                                                                       \
        _Pragma("unroll") for (int i_ = 0; i_ < 4; i_++) {                     \
            GLOAD_LDS16(gA[i_], &As[b][(i_ * 32 + w * 8) * 64]);               \
            GLOAD_LDS16(gB[i_], &Bs[b][(i_ * 32 + w * 8) * 64]);               \
            gA[i_] += 64; gB[i_] += 64;                                        \
        }                                                                      \
    } while (0)

    STGQ(0);
    STGQ(1);
    const int nk = K >> 6;
    for (int it = 0; it < nk; it++) {
        const int buf = it & 1;
        if (it + 1 < nk) {
            asm volatile("s_waitcnt vmcnt(8)" ::: "memory");
        } else {
            asm volatile("s_waitcnt vmcnt(0)" ::: "memory");
        }
        __builtin_amdgcn_sched_barrier(0);
        __builtin_amdgcn_s_barrier();
        __builtin_amdgcn_sched_barrier(0);
#pragma unroll
        for (int s = 0; s < 2; s++) {
            bf16x8 af[4], bfr[4];
#pragma unroll
            for (int i = 0; i < 4; i++) {
                af[i] = *reinterpret_cast<const bf16x8*>(&As[buf][abase[i] + ph[s]]);
                bfr[i] = *reinterpret_cast<const bf16x8*>(&Bs[buf][bbase[i] + ph[s]]);
            }
#pragma unroll
            for (int i = 0; i < 4; i++)
#pragma unroll
                for (int j = 0; j < 4; j++)
                    acc[i][j] = __builtin_amdgcn_mfma_f32_16x16x32_bf16(
                        af[i], bfr[j], acc[i][j], 0, 0, 0);
        }
        __builtin_amdgcn_sched_barrier(0);
        __builtin_amdgcn_s_barrier();
        __builtin_amdgcn_sched_barrier(0);
        if (it + 2 < nk) STGQ(buf);
    }
#undef STGQ

    const int ccol = lane & 15;
    const int crow = (lane >> 4) << 2;
    unsigned short* dst;
    int nbase;
    if (qk) {
        dst = (n0 < 1024) ? q : kb;
        nbase = n0 & 1023;
    } else {
        dst = vT;
        nbase = n0;
    }
    const int ldc = qk ? 1024 : 4096;
#pragma unroll
    for (int i = 0; i < 4; i++) {
#pragma unroll
        for (int j = 0; j < 4; j++) {
            int col = nbase + ncol + j * 16 + ccol;
#pragma unroll
            for (int r = 0; r < 4; r++) {
                int row = m0 + mrow + i * 16 + crow + r;
                dst[(size_t)row * ldc + col] = f2bf(acc[i][j][r]);
            }
        }
    }
}

// ---------------------------------------------------------------------------
// MFMA causal flash attention v6+T5 + FUSED deferred weight transposes.
// Blocks [0,512): attention (bh = id&31, pair = id>>5 — identical mapping
// to the old (32,16) 2D grid).  Blocks [512,2816): transpose+cast of
// wo/wf1/wf2 (consumed only after attn) — rides in attn's idle CU slots
// (attn is grid-limited at 2 blocks/CU, 4.7% HBM).  Transpose stages via
// a small bf16 LDS tile (8.3 KB; total 48.3 KB -> 3 blocks/CU).
// ---------------------------------------------------------------------------
__global__ __launch_bounds__(256) void attn_mfma(
    const unsigned short* __restrict__ Q,   // [4096][1024]
    const unsigned short* __restrict__ K,   // [4096][1024]
    const unsigned short* __restrict__ Vt,  // [1024][4096]
    unsigned short* __restrict__ O,         // [4096][1024]
    const float* __restrict__ wo,
    const float* __restrict__ wf1,
    const float* __restrict__ wf2,
    unsigned short* __restrict__ woT,
    unsigned short* __restrict__ wf1T,
    unsigned short* __restrict__ wf2T) {
    __shared__ unsigned short Ks[2][64 * 64];
    __shared__ unsigned short Vs[2][64 * 64];
    __shared__ unsigned short Ps[4][16 * 64];
    __shared__ unsigned short Tt[64][65];   // transpose staging, 8.3 KB

    const int gid = blockIdx.x;
    const int t = threadIdx.x;

    if (gid >= 512) {
        // ---- deferred weight transpose+cast ----
        int id = gid - 512;
        const float* src; unsigned short* dst; int Kd, Nd, lid;
        if (id < 256)        { src = wo;  dst = woT;  Kd = 1024; Nd = 1024; lid = id; }
        else if (id < 1280)  { src = wf1; dst = wf1T; Kd = 1024; Nd = 4096; lid = id - 256; }
        else                 { src = wf2; dst = wf2T; Kd = 4096; Nd = 1024; lid = id - 1280; }
        int tn = Nd >> 6;
        int k0 = (lid / tn) << 6, n0 = (lid % tn) << 6;
        int rr = t >> 6, cc = t & 63;
#pragma unroll
        for (int i = 0; i < 16; i++) {
            int r = i * 4 + rr;
            Tt[r][cc] = f2bf(src[(size_t)(k0 + r) * Nd + n0 + cc]);
        }
        __syncthreads();
#pragma unroll
        for (int i = 0; i < 16; i++) {
            int r = i * 4 + rr;
            dst[(size_t)(n0 + r) * Kd + k0 + cc] = Tt[cc][r];
        }
        return;
    }

    const int w = t >> 6, lane = t & 63;
    const int l15 = lane & 15, l4 = lane >> 4;
    const int bh = gid & 31;      // 0..31  (same-bh -> same XCD)
    const int b = bh >> 4, h = bh & 15;
    const int pair = gid >> 5;    // 0..15

    const int sr = (w << 3) + (lane >> 3);   // 0..31
    const int sc = lane & 7;
    const int c = sc ^ (sr & 7);
    const unsigned short* kbase = K + ((size_t)(b * SEQ)) * EMB + h * HD;
    const unsigned short* vbase = Vt + ((size_t)(h * HD)) * (size_t)NTOK + (size_t)b * SEQ;
    unsigned short* Pw = &Ps[w][0];

#define STAGE(k0s, buf)                                                        \
    do {                                                                       \
        GLOAD_LDS16(kbase + (size_t)((k0s) + sr) * EMB + c * 8,                \
                    &Ks[buf][(w << 3) * 64]);                                  \
        GLOAD_LDS16(kbase + (size_t)((k0s) + sr + 32) * EMB + c * 8,           \
                    &Ks[buf][((w << 3) + 32) * 64]);                           \
        GLOAD_LDS16(vbase + (size_t)sr * NTOK + (k0s) + c * 8,                 \
                    &Vs[buf][(w << 3) * 64]);                                  \
        GLOAD_LDS16(vbase + (size_t)(sr + 32) * NTOK + (k0s) + c * 8,          \
                    &Vs[buf][((w << 3) + 32) * 64]);                           \
    } while (0)

    const float C1 = 0.125f * 1.4426950408889634f;  // 1/sqrt(64) * log2e
    const float C2 = 3.0f * 1.4426950408889634f;    // fixed max = 3

#pragma unroll
    for (int phase = 0; phase < 2; phase++) {
        const int qt = phase ? pair : (31 - pair);
        const int q0 = qt * 64;

        const unsigned short* qg =
            Q + ((size_t)(b * SEQ + q0 + w * 16 + l15)) * EMB + h * HD + l4 * 8;
        bf16x8 qf0 = *(const bf16x8*)qg;
        bf16x8 qf1 = *(const bf16x8*)(qg + 32);
        const int qrow = q0 + w * 16 + l15;   // this lane's single q-row

        float ls[4] = {0.f, 0.f, 0.f, 0.f};
        f32x4 Oacc[4];
#pragma unroll
        for (int j = 0; j < 4; j++) Oacc[j] = (f32x4){0.f, 0.f, 0.f, 0.f};

        const int ntiles = qt + 1;
        __syncthreads();
        STAGE(0, 0);
        for (int tile = 0; tile < ntiles; tile++) {
            const int k0 = tile * 64;
            const int buf = tile & 1;
            __syncthreads();
            if (tile + 1 < ntiles) STAGE(k0 + 64, buf ^ 1);

            // S^T[k][q]: lane holds q = qrow, k = k0 + 16j + 4*l4 + r
            f32x4 S[4];
#pragma unroll
            for (int j = 0; j < 4; j++) S[j] = (f32x4){0.f, 0.f, 0.f, 0.f};
            __builtin_amdgcn_s_setprio(1);
#pragma unroll
            for (int s = 0; s < 2; s++) {
                bf16x8 qf = s ? qf1 : qf0;
#pragma unroll
                for (int j = 0; j < 4; j++) {
                    int rk = 16 * j + l15;
                    int phys = (s * 4 + l4) ^ (rk & 7);
                    bf16x8 kf = *(const bf16x8*)&Ks[buf][rk * 64 + phys * 8];
                    S[j] = __builtin_amdgcn_mfma_f32_16x16x32_bf16(kf, qf, S[j], 0, 0, 0);
                }
            }
            __builtin_amdgcn_s_setprio(0);

            if (tile == ntiles - 1) {
#pragma unroll
                for (int j = 0; j < 4; j++)
#pragma unroll
                    for (int r = 0; r < 4; r++) {
                        float e = exp2f(S[j][r] * C1 - C2);
                        if (k0 + 16 * j + 4 * l4 + r > qrow) e = 0.f;
                        S[j][r] = e;
                    }
            } else {
#pragma unroll
                for (int j = 0; j < 4; j++)
#pragma unroll
                    for (int r = 0; r < 4; r++)
                        S[j][r] = exp2f(S[j][r] * C1 - C2);
            }

            // pack P[q][k] into LDS: b64 per j (k = 16j+4*l4 .. +3),
            // chunk-XOR swizzle by (q&7) -> conflict-light write & b128 read
#pragma unroll
            for (int j = 0; j < 4; j++) {
                ls[j] += S[j][0] + S[j][1] + S[j][2] + S[j][3];
                unsigned int lo = cvt_pk_bf16(S[j][0], S[j][1]);
                unsigned int hi = cvt_pk_bf16(S[j][2], S[j][3]);
                int chunk = (2 * j + (l4 >> 1)) ^ (l15 & 7);
                uint2 val; val.x = lo; val.y = hi;
                *reinterpret_cast<uint2*>(&Pw[l15 * 64 + chunk * 8 + (l4 & 1) * 4]) = val;
            }

            // O^T = V^T * P^T: lane holds q = qrow, d = 16j + 4*l4 + r
            __builtin_amdgcn_s_setprio(1);
#pragma unroll
            for (int s = 0; s < 2; s++) {
                int pch = (4 * s + l4) ^ (l15 & 7);
                bf16x8 pf = *(const bf16x8*)&Pw[l15 * 64 + pch * 8];
#pragma unroll
                for (int j = 0; j < 4; j++) {
                    int rv = 16 * j + l15;
                    int vph = (s * 4 + l4) ^ (rv & 7);
                    bf16x8 vf = *(const bf16x8*)&Vs[buf][rv * 64 + vph * 8];
                    Oacc[j] = __builtin_amdgcn_mfma_f32_16x16x32_bf16(vf, pf, Oacc[j], 0, 0, 0);
                }
            }
            __builtin_amdgcn_s_setprio(0);
        }

        float l = ls[0] + ls[1] + ls[2] + ls[3];
        l += __shfl_xor(l, 16, 64);
        l += __shfl_xor(l, 32, 64);
        float inv = 1.f / l;
        size_t rowb = (size_t)(b * SEQ + qrow) * EMB + h * HD;
#pragma unroll
        for (int j = 0; j < 4; j++) {
            unsigned int lo = cvt_pk_bf16(Oacc[j][0] * inv, Oacc[j][1] * inv);
            unsigned int hi = cvt_pk_bf16(Oacc[j][2] * inv, Oacc[j][3] * inv);
            uint2 val; val.x = lo; val.y = hi;
            *reinterpret_cast<uint2*>(&O[rowb + 16 * j + 4 * l4]) = val;
        }
    }
#undef STAGE
}

// ---------------------------------------------------------------------------
// launch
// ---------------------------------------------------------------------------
extern "C" void kernel_launch(void* const* d_in, const int* in_sizes, int n_in,
                              void* d_out, int out_size, void* d_ws, size_t ws_size,
                              hipStream_t stream) {
    const float* x     = (const float*)d_in[0];
    const float* w_q   = (const float*)d_in[1];
    const float* w_k   = (const float*)d_in[2];
    const float* w_v   = (const float*)d_in[3];
    const float* w_o   = (const float*)d_in[4];
    const float* b_o   = (const float*)d_in[5];
    const float* ln1s  = (const float*)d_in[6];
    const float* ln1b  = (const float*)d_in[7];
    const float* ln2s  = (const float*)d_in[8];
    const float* ln2b  = (const float*)d_in[9];
    const float* w_ff1 = (const float*)d_in[10];
    const float* b_ff1 = (const float*)d_in[11];
    const float* w_ff2 = (const float*)d_in[12];
    const float* b_ff2 = (const float*)d_in[13];
    float* out = (float*)d_out;

    char* p = (char*)d_ws;
    unsigned short* lnO  = (unsigned short*)p; p += (size_t)NTOK * EMB * 2;      // 8 MB
    unsigned short* q    = (unsigned short*)p; p += (size_t)NTOK * EMB * 2;
    unsigned short* kbuf = (unsigned short*)p; p += (size_t)NTOK * EMB * 2;
    unsigned short* vT   = (unsigned short*)p; p += (size_t)NTOK * EMB * 2;
    unsigned short* ctx  = (unsigned short*)p; p += (size_t)NTOK * EMB * 2;      // attn out, later LN2 out
    unsigned short* ff1a = (unsigned short*)p; p += (size_t)NTOK * FF_DIM * 2;   // 32 MB
    unsigned short* wqkT = (unsigned short*)p; p += (size_t)2 * EMB * EMB * 2;   // 4 MB
    unsigned short* wvT  = (unsigned short*)p; p += (size_t)EMB * EMB * 2;
    unsigned short* woT  = (unsigned short*)p; p += (size_t)EMB * EMB * 2;
    unsigned short* wf1T = (unsigned short*)p; p += (size_t)FF_DIM * EMB * 2;    // 8 MB
    unsigned short* wf2T = (unsigned short*)p; p += (size_t)EMB * FF_DIM * 2;    // 8 MB

    dim3 blk(256);
    dim3 gS64(NTOK / 64, EMB / 64);         // 64 m x 16 n = 1024 blocks = 4/CU
    dim3 gFF1(NTOK / 128, FF_DIM / 128);    // 32 m x 32 n = 1024
    dim3 gAttn(512 + 2304);                 // 512 attn + 2304 deferred transposes

    // prep: wq/wk/wv transpose (768) + LN1 (4096)
    prep_kernel<<<768 + NTOK, blk, 0, stream>>>(
        w_q, w_k, w_v,
        wqkT, wqkT + (size_t)EMB * EMB, wvT,
        x, ln1s, ln1b, lnO);
    qkv_gemm<<<768, blk, 0, stream>>>(lnO, wqkT, wvT, q, kbuf, vT);
    // attn + deferred wo/wf1/wf2 transposes (fill idle CU slots)
    attn_mfma<<<gAttn, blk, 0, stream>>>(q, kbuf, vT, ctx,
                                         w_o, w_ff1, w_ff2, woT, wf1T, wf2T);
    // O-proj fused: out = x + b_o + ctx @ w_o   (64x64 tiles, 1024 blocks)
    mfma_gemm_s64<1><<<gS64, blk, 0, stream>>>(ctx, woT, out, b_o, x, NTOK, EMB, EMB);
    // LN2: out -> ctx (bf16)
    ln_kernel<<<NTOK, blk, 0, stream>>>(out, ln2s, ln2b, ctx);
    // FF1 + cheap gelu epilogue
    ff1_gemm<<<gFF1, blk, 0, stream>>>(ctx, wf1T, ff1a, b_ff1, NTOK, FF_DIM, EMB);
    // FF2 anchor + counted-vmcnt depth-2: out += ff1a @ w_ff2 + b_ff2
    ff2_gemm<<<gS64, blk, 0, stream>>>(ff1a, wf2T, out, b_ff2, NTOK, EMB, FF_DIM);
}